// Round 1
// baseline (292.158 us; speedup 1.0000x reference)
//
#include <hip/hip_runtime.h>
#include <hip/hip_bf16.h>
#include <math.h>

// Problem constants
#define B_SZ   4
#define T_LEN  2048
#define DM     1024
#define NH     16
#define DH     64
#define INNER  1024          // NH*DH
#define NROWS  (B_SZ*T_LEN)  // 8192
#define NQ     (NROWS*INNER) // elements per Q/K/V/Y buffer
#define CH     64            // chunk length
#define NCH    (T_LEN/CH)    // 32 chunks

typedef __bf16 bf16x8 __attribute__((ext_vector_type(8)));
typedef __bf16 bf16x4 __attribute__((ext_vector_type(4)));
typedef float  f32x4  __attribute__((ext_vector_type(4)));
typedef __attribute__((address_space(3))) void*       lds_vp;
typedef const __attribute__((address_space(1))) void* gbl_vp;

// Swizzled index into a 64x64 bf16 LDS tile: 8-elem blocks rotated by row>>2.
__device__ __forceinline__ int swz(int row, int col) {
    return (row << 6) + ((((col >> 3) + (row >> 2)) & 7) << 3) + (col & 7);
}

// ---------------------------------------------------------------------------
// Weight transpose + cast: W (K x N fp32, row-major) -> WT (N x K bf16).
// ---------------------------------------------------------------------------
__global__ __launch_bounds__(256) void wt_cast_transpose(const float* __restrict__ Wq,
                                                         const float* __restrict__ Wk,
                                                         const float* __restrict__ Wv,
                                                         const float* __restrict__ Wo,
                                                         __bf16* __restrict__ WqT,
                                                         __bf16* __restrict__ WkT,
                                                         __bf16* __restrict__ WvT,
                                                         __bf16* __restrict__ WoT) {
    __shared__ float tile[64][65];
    const float* W;
    __bf16* WT;
    if      (blockIdx.z == 0) { W = Wq; WT = WqT; }
    else if (blockIdx.z == 1) { W = Wk; WT = WkT; }
    else if (blockIdx.z == 2) { W = Wv; WT = WvT; }
    else                      { W = Wo; WT = WoT; }

    const int k0 = blockIdx.y * 64, n0 = blockIdx.x * 64;
    const int tr  = threadIdx.x >> 4;        // 0..15
    const int tc4 = (threadIdx.x & 15) * 4;  // 0..60

#pragma unroll
    for (int r = 0; r < 4; r++) {
        const int k = tr + 16 * r;
        const float4 v = *(const float4*)(W + (size_t)(k0 + k) * DM + n0 + tc4);
        tile[k][tc4 + 0] = v.x;
        tile[k][tc4 + 1] = v.y;
        tile[k][tc4 + 2] = v.z;
        tile[k][tc4 + 3] = v.w;
    }
    __syncthreads();
#pragma unroll
    for (int r = 0; r < 4; r++) {
        const int n = tr + 16 * r;
        bf16x4 o;
#pragma unroll
        for (int j = 0; j < 4; j++) o[j] = (__bf16)tile[tc4 + j][n];
        *(bf16x4*)(WT + (size_t)(n0 + n) * DM + k0 + tc4) = o;
    }
}

// ---------------------------------------------------------------------------
// 8-phase pipelined bf16 MFMA GEMM (T2+T3+T4+T5 stack, guide §5/§5.5).
//   C[m0:+256][n0c:+128] = A[m0:+256][0:1024] * BT[n0bt:+128][0:1024]^T
//   512 threads = 8 waves (4M x 2N), per-wave 64x64 output.
//   K-tile = 64, split into two K=32 phases; per phase:
//     8 swizzled ds_read_b128 || 3 global_load_lds prefetch issues
//     -> s_barrier -> lgkmcnt(0)+sched_barrier -> setprio(1) 16 MFMA
//   Counted vmcnt(3) once per K-tile (never 0 in steady state): staging
//   stays in flight ACROSS barriers (T4).  LDS 96 KiB, 1 block/CU.
//   Bank swizzle: 16B slot ^= (row>>1)&3 -> 2-way residual (free, m136);
//   applied on BOTH sides: pre-swizzled global source (global_load_lds
//   writes linearly) + swizzled ds_read offset (rule 21).
// ---------------------------------------------------------------------------
#define A_LOFF(buf_, kh_) ((buf_) * 32768 + (kh_) * 16384)
#define B_LOFF(buf_, kh_) (65536 + (buf_) * 16384 + (kh_) * 8192)

template <typename CT>
__device__ __forceinline__ void gemm_8ph_body(const __bf16* __restrict__ A,
                                              const __bf16* __restrict__ BT,
                                              CT* __restrict__ C,
                                              int m0, int n0bt, int n0c) {
    // A halves: [buf][kh][row 0..255][32 bf16]  = 64 KiB
    // B halves: [buf][kh][row 0..127][32 bf16]  = 32 KiB
    __shared__ __align__(16) char lds[98304];

    const int tid  = threadIdx.x;
    const int wid  = tid >> 6;       // 0..7
    const int lane = tid & 63;
    const int wm = wid >> 1;         // 0..3 : 64-row stripe
    const int wn = wid & 1;          // 0..1 : 64-col stripe
    const int frow = lane & 15, quad = lane >> 4;

    // swizzled ds_read byte offsets within one kh-half (loop-invariant)
    int offA[4], offB[4];
#pragma unroll
    for (int i = 0; i < 4; ++i) {
        const int ra = wm * 64 + i * 16 + frow;
        offA[i] = ra * 64 + ((quad ^ ((ra >> 1) & 3)) << 4);
        const int rb = wn * 64 + i * 16 + frow;
        offB[i] = rb * 64 + ((quad ^ ((rb >> 1) & 3)) << 4);
    }

    // staging: per-lane pre-swizzled global source (16 rows x 64B per instr)
    const int lr = lane >> 2;                                  // row in region
    const int cs = ((lane & 3) ^ ((lane >> 3) & 3)) << 3;      // elem col (swz)
    const __bf16* gA0 = A  + (size_t)(m0 + (wid * 2 + 0) * 16 + lr) * 1024 + cs;
    const __bf16* gA1 = A  + (size_t)(m0 + (wid * 2 + 1) * 16 + lr) * 1024 + cs;
    const __bf16* gB  = BT + (size_t)(n0bt + wid * 16 + lr) * 1024 + cs;

#define STG_A(t_, kh_) do {                                                        \
        __builtin_amdgcn_global_load_lds((gbl_vp)(gA0 + (t_) * 64 + (kh_) * 32),   \
            (lds_vp)(lds + A_LOFF((t_) & 1, kh_) + (wid * 2 + 0) * 1024), 16, 0, 0); \
        __builtin_amdgcn_global_load_lds((gbl_vp)(gA1 + (t_) * 64 + (kh_) * 32),   \
            (lds_vp)(lds + A_LOFF((t_) & 1, kh_) + (wid * 2 + 1) * 1024), 16, 0, 0); \
    } while (0)
#define STG_B(t_, kh_)                                                             \
        __builtin_amdgcn_global_load_lds((gbl_vp)(gB + (t_) * 64 + (kh_) * 32),    \
            (lds_vp)(lds + B_LOFF((t_) & 1, kh_) + wid * 1024), 16, 0, 0)

    f32x4 acc[4][4];
#pragma unroll
    for (int i = 0; i < 4; i++)
#pragma unroll
        for (int j = 0; j < 4; j++) acc[i][j] = (f32x4)0.f;

    // prologue: tile0 fully + tile1 (kh=0 halves); leave exactly 3 in flight
    STG_A(0, 0); STG_A(0, 1); STG_B(0, 0); STG_B(0, 1);
    STG_A(1, 0); STG_B(1, 0);
    asm volatile("s_waitcnt vmcnt(3)" ::: "memory");
    asm volatile("s_barrier" ::: "memory");

    // one phase: ds_read frags || prefetch issue -> bar -> lgkm0 -> MFMA -> [vm] -> bar
#define PHASE(u_, kh_, STG_STMT, VM_STMT)                                          \
    {                                                                              \
        const char* Ab_ = lds + A_LOFF((u_) & 1, kh_);                             \
        const char* Bb_ = lds + B_LOFF((u_) & 1, kh_);                             \
        bf16x8 af_[4], bfr_[4];                                                    \
        _Pragma("unroll")                                                          \
        for (int i_ = 0; i_ < 4; ++i_) {                                           \
            af_[i_]  = *(const bf16x8*)(Ab_ + offA[i_]);                           \
            bfr_[i_] = *(const bf16x8*)(Bb_ + offB[i_]);                           \
        }                                                                          \
        STG_STMT;                                                                  \
        asm volatile("s_barrier" ::: "memory");                                    \
        asm volatile("s_waitcnt lgkmcnt(0)" ::: "memory");                         \
        __builtin_amdgcn_sched_barrier(0);                                         \
        __builtin_amdgcn_s_setprio(1);                                             \
        _Pragma("unroll")                                                          \
        for (int mi_ = 0; mi_ < 4; ++mi_)                                          \
            _Pragma("unroll")                                                      \
            for (int nj_ = 0; nj_ < 4; ++nj_)                                      \
                acc[mi_][nj_] = __builtin_amdgcn_mfma_f32_16x16x32_bf16(           \
                    af_[mi_], bfr_[nj_], acc[mi_][nj_], 0, 0, 0);                  \
        __builtin_amdgcn_s_setprio(0);                                             \
        VM_STMT;                                                                   \
        asm volatile("s_barrier" ::: "memory");                                    \
    }

    // main loop: 16 K-tiles; steady schedule for u=0..13, tail peeled
    for (int u = 0; u < 14; ++u) {
        PHASE(u, 0, { STG_A(u + 1, 1); STG_B(u + 1, 1); }, );
        PHASE(u, 1, { STG_A(u + 2, 0); STG_B(u + 2, 0); },
              asm volatile("s_waitcnt vmcnt(3)" ::: "memory"));
    }
    PHASE(14, 0, { STG_A(15, 1); STG_B(15, 1); }, );
    PHASE(14, 1, { }, asm volatile("s_waitcnt vmcnt(0)" ::: "memory"));
    PHASE(15, 0, { }, );
    PHASE(15, 1, { }, );

#undef PHASE
#undef STG_A
#undef STG_B

    // epilogue: C-write (same fragment mapping as verified base kernel)
    const int cr = quad * 4, cc = frow;
#pragma unroll
    for (int mi = 0; mi < 4; ++mi) {
#pragma unroll
        for (int nj = 0; nj < 4; ++nj) {
            CT* Cp = C + (size_t)(m0 + wm * 64 + mi * 16 + cr) * 1024
                       + n0c + wn * 64 + nj * 16 + cc;
#pragma unroll
            for (int r = 0; r < 4; r++) Cp[(size_t)r * 1024] = (CT)acc[mi][nj][r];
        }
    }
}

// Fused QKV: BTall = [WqT|WkT|WvT] as [3072][1024]; QKV = [Q|K|V] contiguous.
// 768 blocks = 32 m-tiles x 24 n-tiles = exactly 3 full rounds on 256 CUs.
// XCD swizzle (T1, bijective: 768 % 8 == 0): each XCD owns a contiguous
// 4-m-tile stripe for L2 locality.
__global__ __launch_bounds__(512, 2) void qkv_gemm_8ph(const __bf16* __restrict__ xb,
                                                       const __bf16* __restrict__ BTall,
                                                       __bf16* __restrict__ QKV) {
    const int id = blockIdx.x;
    const int wg = (id & 7) * 96 + (id >> 3);
    const int mt = wg / 24, nt = wg % 24;
    const int mat = nt >> 3;
    gemm_8ph_body<__bf16>(xb, BTall, QKV + (size_t)mat * NQ,
                          mt * 256, nt * 128, (nt & 7) * 128);
}

// Output projection: 256 blocks = exactly 1 full round.
__global__ __launch_bounds__(512, 2) void out_gemm_8ph(const __bf16* __restrict__ Yb,
                                                       const __bf16* __restrict__ WoT,
                                                       float* __restrict__ Cout) {
    const int id = blockIdx.x;
    const int wg = (id & 7) * 32 + (id >> 3);
    const int mt = wg >> 3, nt = wg & 7;
    gemm_8ph_body<float>(Yb, WoT, Cout, mt * 256, nt * 128, nt * 128);
}

// ---------------------------------------------------------------------------
// Fused gates + x cast (MFMA).  128 blocks x 256 thr; block = 64 rows.
// ---------------------------------------------------------------------------
#define WGS 1032   // lWg row stride (bf16): 516 dw, 4-dw bank rotation
#define LAS 40     // lA row stride (bf16): 20 dw rotation, 16B aligned
__global__ __launch_bounds__(256) void gates_fused(const float* __restrict__ x,
                                                   const float* __restrict__ Wa,
                                                   const float* __restrict__ ba,
                                                   const float* __restrict__ Wb,
                                                   const float* __restrict__ bb,
                                                   float* __restrict__ AlphaT,
                                                   float* __restrict__ BetaT,
                                                   __bf16* __restrict__ xb) {
    __shared__ __align__(16) __bf16 lWg[32 * WGS];
    __shared__ __align__(16) __bf16 lA[64 * LAS];

    const int tid = threadIdx.x;
    const int wid = tid >> 6, lane = tid & 63;
    const int quad = lane >> 4, frow = lane & 15;
    const int m0 = blockIdx.x * 64;

    // ---- stage W^T (bf16) into LDS ----
    {
        const int kbase = tid * 4;
#pragma unroll
        for (int j = 0; j < 4; j++) {
            const int k = kbase + j;
            const float4* war = (const float4*)(Wa + (size_t)k * NH);
            const float4* wbr = (const float4*)(Wb + (size_t)k * NH);
#pragma unroll
            for (int q = 0; q < 4; q++) {
                const float4 a = war[q], bq = wbr[q];
                lWg[(q * 4 + 0) * WGS + k] = (__bf16)a.x;
                lWg[(q * 4 + 1) * WGS + k] = (__bf16)a.y;
                lWg[(q * 4 + 2) * WGS + k] = (__bf16)a.z;
                lWg[(q * 4 + 3) * WGS + k] = (__bf16)a.w;
                lWg[(16 + q * 4 + 0) * WGS + k] = (__bf16)bq.x;
                lWg[(16 + q * 4 + 1) * WGS + k] = (__bf16)bq.y;
                lWg[(16 + q * 4 + 2) * WGS + k] = (__bf16)bq.z;
                lWg[(16 + q * 4 + 3) * WGS + k] = (__bf16)bq.w;
            }
        }
    }
    const float bias_a = ba[frow];
    const float bias_b = bb[frow];

    // ---- pipelined K loop ----
    const int rrow = tid >> 2;          // 0..63
    const int rk   = (tid & 3) * 8;     // 0,8,16,24
    const float* xrow = x + (size_t)(m0 + rrow) * DM + rk;
    float4 c0 = *(const float4*)(xrow + 0);
    float4 c1 = *(const float4*)(xrow + 4);

    f32x4 acc[2];
    acc[0] = (f32x4)0.f; acc[1] = (f32x4)0.f;

    for (int k0 = 0; k0 < DM; k0 += 32) {
        __syncthreads();   // prev iter's lA reads done (also covers lWg stage)
        bf16x8 xv;
        xv[0] = (__bf16)c0.x; xv[1] = (__bf16)c0.y; xv[2] = (__bf16)c0.z; xv[3] = (__bf16)c0.w;
        xv[4] = (__bf16)c1.x; xv[5] = (__bf16)c1.y; xv[6] = (__bf16)c1.z; xv[7] = (__bf16)c1.w;
        *(bf16x8*)&lA[rrow * LAS + rk] = xv;
        *(bf16x8*)(xb + (size_t)(m0 + rrow) * DM + k0 + rk) = xv;
        if (k0 + 32 < DM) {
            c0 = *(const float4*)(xrow + k0 + 32);
            c1 = *(const float4*)(xrow + k0 + 36);
        }
        __syncthreads();
        const bf16x8 af = *(const bf16x8*)&lA[(wid * 16 + frow) * LAS + quad * 8];
#pragma unroll
        for (int ct = 0; ct < 2; ct++) {
            const bf16x8 bf = *(const bf16x8*)&lWg[(ct * 16 + frow) * WGS + k0 + quad * 8];
            acc[ct] = __builtin_amdgcn_mfma_f32_16x16x32_bf16(af, bf, acc[ct], 0, 0, 0);
        }
    }

    // ---- sigmoid epilogue, transposed store ----
#pragma unroll
    for (int ct = 0; ct < 2; ct++) {
        const float bias = (ct == 0) ? bias_a : bias_b;
        float* dst = (ct == 0) ? AlphaT : BetaT;
#pragma unroll
        for (int r = 0; r < 4; r++) {
            const int row = m0 + wid * 16 + quad * 4 + r;
            const float s = acc[ct][r] + bias;
            dst[(size_t)frow * NROWS + row] = 1.f / (1.f + __expf(-s));
        }
    }
}

// ---------------------------------------------------------------------------
// Pass A (MFMA, bf16 I/O): per (b,h,c), 256 threads = 4 waves.
// ---------------------------------------------------------------------------
__global__ __launch_bounds__(256) void chunk_ds(const __bf16* __restrict__ Q,
                                                const __bf16* __restrict__ K,
                                                __bf16* __restrict__ V,
                                                const float* __restrict__ AlphaT,
                                                const float* __restrict__ BetaT,
                                                float* __restrict__ Dec,
                                                float* __restrict__ DS,
                                                float* __restrict__ ExpT) {
    __shared__ __align__(16) __bf16 Qb[64 * 64];
    __shared__ __align__(16) __bf16 Kb[64 * 64];
    __shared__ __align__(16) __bf16 KTs[64 * 64];  // [j][s] = swd_s * kn[s][j]
    __shared__ __align__(16) __bf16 VTb[64 * 64];  // [i][s] = V[s][i]
    __shared__ __align__(16) __bf16 Ab[64 * 64];   // [t][s]
    __shared__ float sla[64], sb[64], swd[64];

    const int blk = blockIdx.x;
    const int c = blk & 31, h = (blk >> 5) & 15, b = blk >> 9;
    const int t0 = c * CH;
    const int tid = threadIdx.x;
    const int wid = tid >> 6, lane = tid & 63;
    const size_t rowbase = ((size_t)(b * T_LEN + t0) * NH + h) * DH;

    // prefetch (16B bf16x8 per matrix per round)
    const int srow = tid >> 3;          // 0..31
    const int scol = (tid & 7) * 8;     // 0..56
    bf16x8 q8[2], k8[2], v8[2];
#pragma unroll
    for (int r = 0; r < 2; r++) {
        const size_t g = rowbase + (size_t)(srow + 32 * r) * INNER + scol;
        q8[r] = *(const bf16x8*)(Q + g);
        k8[r] = *(const bf16x8*)(K + g);
        v8[r] = *(const bf16x8*)(V + g);
    }

    // gates: prefix-sum of log(alpha) over the chunk (wave 0, coalesced)
    if (tid < 64) {
        const int t = tid;
        const size_t gaT = (size_t)h * NROWS + b * T_LEN + t0 + t;
        const float a  = AlphaT[gaT];
        const float bt = BetaT[gaT];
        float xx = logf(a);
#pragma unroll
        for (int off = 1; off < 64; off <<= 1) {
            const float y = __shfl_up(xx, off, 64);
            if (t >= off) xx += y;
        }
        const float la63 = __shfl(xx, 63, 64);
        sla[t] = xx;
        sb[t]  = bt;
        swd[t] = bt * __expf(la63 - xx);
        ExpT[gaT] = __expf(xx);
        if (t == 63) Dec[(size_t)(b * NH + h) * NCH + c] = __expf(la63);
    }
    __syncthreads();

    // stage to LDS: normalize k rows (8 lanes per row -> 3 shfl_xor)
#pragma unroll
    for (int r = 0; r < 2; r++) {
        const int row = srow + 32 * r;
        float kf[8];
        float ss = 0.f;
#pragma unroll
        for (int j = 0; j < 8; j++) { kf[j] = (float)k8[r][j]; ss += kf[j] * kf[j]; }
        ss += __shfl_xor(ss, 1, 64);
        ss += __shfl_xor(ss, 2, 64);
        ss += __shfl_xor(ss, 4, 64);
        const float scale = 1.f / fmaxf(sqrtf(ss), 1e-12f);
        const float w = swd[row];
        bf16x8 kn8;
#pragma unroll
        for (int j = 0; j < 8; j++) {
            const float kn = kf[j] * scale;
            kn8[j] = (__bf16)kn;
            KTs[swz(scol + j, row)] = (__bf16)(w * kn);
            VTb[swz(scol + j, row)] = v8[r][j];
        }
        *(bf16x8*)&Qb[swz(row, scol)] = q8[r];
        *(bf16x8*)&Kb[swz(row, scol)] = kn8;
    }
    __syncthreads();

    const int quad = lane >> 4;
    const int frow = lane & 15;
    const int tw = wid * 16;   // this wave's 16-row output stripe

    // ---- G = Q K^T ----
    f32x4 accG[4];
#pragma unroll
    for (int i = 0; i < 4; i++) accG[i] = (f32x4)0.f;
#pragma unroll
    for (int ks = 0; ks < 2; ks++) {
        const int ko = quad * 8 + 32 * ks;
        const bf16x8 aq = *(const bf16x8*)&Qb[swz(tw + frow, ko)];
#pragma unroll
        for (int st = 0; st < 4; st++) {
            const bf16x8 bk = *(const bf16x8*)&Kb[swz(st * 16 + frow, ko)];
            accG[st] = __builtin_amdgcn_mfma_f32_16x16x32_bf16(aq, bk, accG[st], 0, 0, 0);
        }
    }
    // ---- mask -> Ab (C layout: row=quad*4+r, col=frow) ----
#pragma unroll
    for (int st = 0; st < 4; st++) {
#pragma unroll
        for (int r = 0; r < 4; r++) {
            const int t = tw + quad * 4 + r;
            const int s = st * 16 + frow;
            const float av = (s <= t) ? __expf(sla[t] - sla[s]) * sb[s] * accG[st][r] : 0.f;
            Ab[swz(t, s)] = (__bf16)av;
        }
    }
    __syncthreads();

    // ---- Y_intra = A V  and  dS = VT * KTs^T ----
    f32x4 accY[4], accD[4];
#pragma unroll
    for (int i = 0; i < 4; i++) { accY[i] = (f32x4)0.f; accD[i] = (f32x4)0.f; }
#pragma unroll
    for (int ks = 0; ks < 2; ks++) {
        const int ko = quad * 8 + 32 * ks;
        const bf16x8 aA = *(const bf16x8*)&Ab[swz(tw + frow, ko)];
        const bf16x8 aV = *(const bf16x8*)&VTb[swz(tw + frow, ko)];
#pragma unroll
        for (int jt = 0; jt < 4; jt++) {
            const bf16x8 bv = *(const bf16x8*)&VTb[swz(jt * 16 + frow, ko)];
            const bf16x8 bk = *(const bf16x8*)&KTs[swz(jt * 16 + frow, ko)];
            accY[jt] = __builtin_amdgcn_mfma_f32_16x16x32_bf16(aA, bv, accY[jt], 0, 0, 0);
            accD[jt] = __builtin_amdgcn_mfma_f32_16x16x32_bf16(aV, bk, accD[jt], 0, 0, 0);
        }
    }
    // write Y_intra (bf16) over V, dS (fp32) to DS
#pragma unroll
    for (int jt = 0; jt < 4; jt++) {
#pragma unroll
        for (int r = 0; r < 4; r++) {
            const int row = tw + quad * 4 + r;
            const size_t g = rowbase + (size_t)row * INNER + jt * 16 + frow;
            V[g]  = (__bf16)accY[jt][r];
            DS[g] = accD[jt][r];
        }
    }
}

// ---------------------------------------------------------------------------
// Pass B1 (serial, tiny): S_{c+1} = Dec_c * S_c + dS_c over 32 chunks per
// (b,h).  Writes each PRE-update state S_c as bf16 to ScB (for chunk_y).
// ---------------------------------------------------------------------------
__global__ __launch_bounds__(256) void chunk_state(const float* __restrict__ DS,
                                                   const float* __restrict__ Dec,
                                                   const float* __restrict__ state_in,
                                                   float* __restrict__ state_out,
                                                   __bf16* __restrict__ ScB) {
    const int blk = blockIdx.x;          // (b,h)
    const int b = blk >> 4, h = blk & 15;
    const int tid = threadIdx.x;
    const int w = tid >> 6;
    const int l = tid & 63;

    float S[16];
    {
        const float* st = state_in + ((size_t)(b * NH + h) * DH + l) * DH + 16 * w;
#pragma unroll
        for (int j4 = 0; j4 < 4; j4++)
            *(float4*)&S[4 * j4] = *(const float4*)(st + 4 * j4);
    }

    for (int c = 0; c < NCH; c++) {
        const int t0 = c * CH;
        const float decay = Dec[(size_t)(b * NH + h) * NCH + c];
        const size_t off = ((size_t)(b * T_LEN + t0 + l) * NH + h) * DH + 16 * w;
        const float* ds = DS + off;
        __bf16* sc = ScB + off;
        float4 dv[4];
#pragma unroll
        for (int j4 = 0; j4 < 4; j4++) dv[j4] = *(const float4*)(ds + 4 * j4);
#pragma unroll
        for (int j4 = 0; j4 < 4; j4++) {
            bf16x4 o;
            o[0] = (__bf16)S[4 * j4 + 0]; o[1] = (__bf16)S[4 * j4 + 1];
            o[2] = (__bf16)S[4 * j4 + 2]; o[3] = (__bf16)S[4 * j4 + 3];
            *(bf16x4*)(sc + 4 * j4) = o;
        }
#pragma unroll
        for (int j4 = 0; j4 < 4; j4++) {
            S[4 * j4 + 0] = decay * S[4 * j4 + 0] + dv[j4].x;
            S[4 * j4 + 1] = decay * S[4 * j4 + 1] + dv[j4].y;
            S[4 * j4 + 2] = decay * S[4 * j4 + 2] + dv[j4].z;
            S[4 * j4 + 3] = decay * S[4 * j4 + 3] + dv[j4].w;
        }
    }

    float* so = state_out + ((size_t)(b * NH + h) * DH + l) * DH + 16 * w;
#pragma unroll
    for (int j4 = 0; j4 < 4; j4++)
        *(float4*)(so + 4 * j4) = *(const float4*)&S[4 * j4];
}

// ---------------------------------------------------------------------------
// Pass B2 (MFMA): Yb[t][i] = bf16( Yb[t][i] + ExpT[t]*sum_j Q[t][j]Sc[i][j] )
// ---------------------------------------------------------------------------
__global__ __launch_bounds__(256) void chunk_y(const __bf16* __restrict__ Q,
                                               const __bf16* __restrict__ ScB,
                                               __bf16* __restrict__ Yb,
                                               const float* __restrict__ ExpT) {
    __shared__ __align__(16) __bf16 Qb[64 * 64];
    __shared__ __align__(16) __bf16 Scb[64 * 64];
    __shared__ float sexp[64];

    const int blk = blockIdx.x;
    const int c = blk & 31, h = (blk >> 5) & 15, b = blk >> 9;
    const int t0 = c * CH;
    const int tid = threadIdx.x;
    const int wid = tid >> 6, lane = tid & 63;
    const size_t rowbase = ((size_t)(b * T_LEN + t0) * NH + h) * DH;

    // prefetch Q / Sc (bf16x8)
    const int srow = tid >> 3;
    const int scol = (tid & 7) * 8;
    bf16x8 q8[2], s8[2];
#pragma unroll
    for (int r = 0; r < 2; r++) {
        const size_t g = rowbase + (size_t)(srow + 32 * r) * INNER + scol;
        q8[r] = *(const bf16x8*)(Q + g);
        s8[r] = *(const bf16x8*)(ScB + g);
    }

    if (tid < 64)
        sexp[tid] = ExpT[(size_t)h * NROWS + b * T_LEN + t0 + tid];

#pragma unroll
    for (int r = 0; r < 2; r++) {
        *(bf16x8*)&Qb[swz(srow + 32 * r, scol)]  = q8[r];
        *(bf16x8*)&Scb[swz(srow + 32 * r, scol)] = s8[r];
    }
    __syncthreads();

    const int quad = lane >> 4;
    const int frow = lane & 15;
    const int tw = wid * 16;

    f32x4 accU[4];
#pragma unroll
    for (int i = 0; i < 4; i++) accU[i] = (f32x4)0.f;
#pragma unroll
    for (int ks = 0; ks < 2; ks++) {
        const int ko = quad * 8 + 32 * ks;
        const bf16x8 aq = *(const bf16x8*)&Qb[swz(tw + frow, ko)];
#pragma unroll
        for (int it = 0; it < 4; it++) {
            const bf16x8 bs = *(const bf16x8*)&Scb[swz(it * 16 + frow, ko)];
            accU[it] = __builtin_amdgcn_mfma_f32_16x16x32_bf16(aq, bs, accU[it], 0, 0, 0);
        }
    }

#pragma unroll
    for (int it = 0; it < 4; it++) {
#pragma unroll
        for (int r = 0; r < 4; r++) {
            const int t = tw + quad * 4 + r;
            const size_t g = rowbase + (size_t)t * INNER + it * 16 + frow;
            Yb[g] = (__bf16)(sexp[t] * accU[it][r] + (float)Yb[g]);
        }
    }
}

// ---------------------------------------------------------------------------
extern "C" void kernel_launch(void* const* d_in, const int* in_sizes, int n_in,
                              void* d_out, int out_size, void* d_ws, size_t ws_size,
                              hipStream_t stream) {
    const float* x     = (const float*)d_in[0];
    const float* state = (const float*)d_in[1];
    const float* Wq    = (const float*)d_in[2];
    const float* Wk    = (const float*)d_in[3];
    const float* Wv    = (const float*)d_in[4];
    const float* Wa    = (const float*)d_in[5];
    const float* ba    = (const float*)d_in[6];
    const float* Wb    = (const float*)d_in[7];
    const float* bb    = (const float*)d_in[8];
    const float* Wo    = (const float*)d_in[9];

    __bf16* Qb    = (__bf16*)d_ws;               // NQ bf16 (raw q, preserved)
    __bf16* Kbf   = Qb + (size_t)NQ;             // NQ bf16 (raw k)
    __bf16* Vbf   = Kbf + (size_t)NQ;            // NQ bf16 (v -> Y_intra -> Y)
    float*  DS    = (float*)(Vbf + (size_t)NQ);  // NQ fp32 (dS)
    float*  AlphaT= DS + (size_t)NQ;             // [NH][NROWS]
    float*  BetaT = AlphaT + (size_t)NROWS * NH;
    float*  ExpT  = BetaT + (size_t)NROWS * NH;  // [NH][NROWS] exp(la_t)
    float*  Dec   = ExpT + (size_t)NROWS * NH;   // per-chunk decay
    __bf16* xb    = (__bf16*)(Dec + (size_t)B_SZ * NH * NCH);
    __bf16* ScB   = xb;                          // reuse: xb dead after qkv gemm
    __bf16* WqT   = xb + (size_t)NQ;             // [WqT|WkT|WvT] contiguous
    __bf16* WkT   = WqT + (size_t)DM * INNER;
    __bf16* WvT   = WkT + (size_t)DM * INNER;
    __bf16* WoT   = WvT + (size_t)DM * INNER;

    float* out  = (float*)d_out;                // (B,T,DM)
    float* Sout = out + (size_t)NQ;             // (B,H,D,D)

    // 0) weights cast+transpose
    wt_cast_transpose<<<dim3(16, 16, 4), 256, 0, stream>>>(Wq, Wk, Wv, Wo,
                                                           WqT, WkT, WvT, WoT);
    // 1) fused gates (MFMA) + x->bf16 cast
    gates_fused<<<NROWS / 64, 256, 0, stream>>>(x, Wa, ba, Wb, bb,
                                                AlphaT, BetaT, xb);
    // 2) Q/K/V projections fused into ONE 8-phase GEMM (M=8192, N=3072):
    //    768 blocks = exactly 3 full rounds on 256 CUs.
    qkv_gemm_8ph<<<768, 512, 0, stream>>>(xb, WqT, Qb);
    // 3) intra-chunk MFMA (+fused knorm): Y_intra -> Vbf, dS -> DS
    chunk_ds<<<B_SZ * NH * NCH, 256, 0, stream>>>(Qb, Kbf, Vbf, AlphaT, BetaT,
                                                  Dec, DS, ExpT);
    // 4) serial inter-chunk state recurrence; Sc -> ScB (bf16)
    chunk_state<<<B_SZ * NH, 256, 0, stream>>>(DS, Dec, state, Sout, ScB);
    // 5) parallel Y_inter MFMA, in-place finalize of Vbf
    chunk_y<<<B_SZ * NH * NCH, 256, 0, stream>>>(Qb, ScB, Vbf, ExpT);
    // 6) output projection (8-phase, 256 blocks = 1 full round)
    out_gemm_8ph<<<256, 512, 0, stream>>>(Vbf, WoT, out);
}

// Round 2
// 287.045 us; speedup vs baseline: 1.0178x; 1.0178x over previous
//
#include <hip/hip_runtime.h>
#include <hip/hip_bf16.h>
#include <math.h>

// Problem constants
#define B_SZ   4
#define T_LEN  2048
#define DM     1024
#define NH     16
#define DH     64
#define INNER  1024          // NH*DH
#define NROWS  (B_SZ*T_LEN)  // 8192
#define NQ     (NROWS*INNER) // elements per Q/K/V/Y buffer
#define CH     64            // chunk length
#define NCH    (T_LEN/CH)    // 32 chunks

typedef __bf16 bf16x8 __attribute__((ext_vector_type(8)));
typedef __bf16 bf16x4 __attribute__((ext_vector_type(4)));
typedef float  f32x4  __attribute__((ext_vector_type(4)));
typedef __attribute__((address_space(3))) void*       lds_vp;
typedef const __attribute__((address_space(1))) void* gbl_vp;

// Swizzled index into a 64x64 bf16 LDS tile: 8-elem blocks rotated by row>>2.
__device__ __forceinline__ int swz(int row, int col) {
    return (row << 6) + ((((col >> 3) + (row >> 2)) & 7) << 3) + (col & 7);
}

// ---------------------------------------------------------------------------
// Weight transpose + cast: W (K x N fp32, row-major) -> WT (N x K bf16).
// ---------------------------------------------------------------------------
__global__ __launch_bounds__(256) void wt_cast_transpose(const float* __restrict__ Wq,
                                                         const float* __restrict__ Wk,
                                                         const float* __restrict__ Wv,
                                                         const float* __restrict__ Wo,
                                                         __bf16* __restrict__ WqT,
                                                         __bf16* __restrict__ WkT,
                                                         __bf16* __restrict__ WvT,
                                                         __bf16* __restrict__ WoT) {
    __shared__ float tile[64][65];
    const float* W;
    __bf16* WT;
    if      (blockIdx.z == 0) { W = Wq; WT = WqT; }
    else if (blockIdx.z == 1) { W = Wk; WT = WkT; }
    else if (blockIdx.z == 2) { W = Wv; WT = WvT; }
    else                      { W = Wo; WT = WoT; }

    const int k0 = blockIdx.y * 64, n0 = blockIdx.x * 64;
    const int tr  = threadIdx.x >> 4;        // 0..15
    const int tc4 = (threadIdx.x & 15) * 4;  // 0..60

#pragma unroll
    for (int r = 0; r < 4; r++) {
        const int k = tr + 16 * r;
        const float4 v = *(const float4*)(W + (size_t)(k0 + k) * DM + n0 + tc4);
        tile[k][tc4 + 0] = v.x;
        tile[k][tc4 + 1] = v.y;
        tile[k][tc4 + 2] = v.z;
        tile[k][tc4 + 3] = v.w;
    }
    __syncthreads();
#pragma unroll
    for (int r = 0; r < 4; r++) {
        const int n = tr + 16 * r;
        bf16x4 o;
#pragma unroll
        for (int j = 0; j < 4; j++) o[j] = (__bf16)tile[tc4 + j][n];
        *(bf16x4*)(WT + (size_t)(n0 + n) * DM + k0 + tc4) = o;
    }
}

// ---------------------------------------------------------------------------
// 3-stage pipelined bf16 MFMA GEMM (T2+T3+T4+T5, deepened prefetch).
//   C[m0:+256][n0c:+128] = A[m0:+256][0:1024] * BT[n0bt:+128][0:1024]^T
//   512 threads = 8 waves (4M x 2N), per-wave 64x64 output.
//   LDS: 3 buffers x (A 256x64 + B 128x64) bf16 = 144 KiB, 1 block/CU.
//   Loads for K-tile u are ISSUED during tile u-2 (3-phase lead ~2300 cy
//   > ~900 cy HBM latency); per-phase counted vmcnt(9) keeps 3 groups of
//   3 global_load_lds in flight -- never drained in steady state (T4).
//   Bank swizzle on BOTH sides (pre-swizzled global source + swizzled
//   ds_read offsets, rule 21); residual 2-way conflict is free (m136).
// ---------------------------------------------------------------------------
#define AOF(b_, kh_) ((b_) * 32768 + (kh_) * 16384)
#define BOF(b_, kh_) (98304 + (b_) * 16384 + (kh_) * 8192)

template <typename CT>
__device__ __forceinline__ void gemm_8ph_body(const __bf16* __restrict__ A,
                                              const __bf16* __restrict__ BT,
                                              CT* __restrict__ C,
                                              int m0, int n0bt, int n0c) {
    __shared__ __align__(16) char lds[147456];

    const int tid  = threadIdx.x;
    const int wid  = tid >> 6;       // 0..7
    const int lane = tid & 63;
    const int wm = wid >> 1;         // 0..3 : 64-row stripe
    const int wn = wid & 1;          // 0..1 : 64-col stripe
    const int frow = lane & 15, quad = lane >> 4;

    // swizzled ds_read byte offsets within one kh-half (loop-invariant)
    int offA[4], offB[4];
#pragma unroll
    for (int i = 0; i < 4; ++i) {
        const int ra = wm * 64 + i * 16 + frow;
        offA[i] = ra * 64 + ((quad ^ ((ra >> 1) & 3)) << 4);
        const int rb = wn * 64 + i * 16 + frow;
        offB[i] = rb * 64 + ((quad ^ ((rb >> 1) & 3)) << 4);
    }

    // staging: per-lane pre-swizzled global source (16 rows x 64B per instr)
    const int lr = lane >> 2;                                  // row in region
    const int cs = ((lane & 3) ^ ((lane >> 3) & 3)) << 3;      // elem col (swz)
    const __bf16* gA0 = A  + (size_t)(m0 + (wid * 2 + 0) * 16 + lr) * 1024 + cs;
    const __bf16* gA1 = A  + (size_t)(m0 + (wid * 2 + 1) * 16 + lr) * 1024 + cs;
    const __bf16* gB  = BT + (size_t)(n0bt + wid * 16 + lr) * 1024 + cs;

    // one staging group: 3 global_load_lds (2 A-chunks + 1 B-chunk)
#define STG3(t_, kh_, b_) do {                                                     \
        __builtin_amdgcn_global_load_lds((gbl_vp)(gA0 + (size_t)(t_) * 64 + (kh_) * 32), \
            (lds_vp)(lds + AOF(b_, kh_) + (wid * 2 + 0) * 1024), 16, 0, 0);        \
        __builtin_amdgcn_global_load_lds((gbl_vp)(gA1 + (size_t)(t_) * 64 + (kh_) * 32), \
            (lds_vp)(lds + AOF(b_, kh_) + (wid * 2 + 1) * 1024), 16, 0, 0);        \
        __builtin_amdgcn_global_load_lds((gbl_vp)(gB  + (size_t)(t_) * 64 + (kh_) * 32), \
            (lds_vp)(lds + BOF(b_, kh_) + wid * 1024), 16, 0, 0);                  \
    } while (0)

#define VM9 asm volatile("s_waitcnt vmcnt(9)" ::: "memory")
#define VM6 asm volatile("s_waitcnt vmcnt(6)" ::: "memory")
#define VM3 asm volatile("s_waitcnt vmcnt(3)" ::: "memory")
#define VM0 asm volatile("s_waitcnt vmcnt(0)" ::: "memory")

    f32x4 acc[4][4];
#pragma unroll
    for (int i = 0; i < 4; i++)
#pragma unroll
        for (int j = 0; j < 4; j++) acc[i][j] = (f32x4)0.f;

    // prologue: stage tiles 0 and 1 fully (12 loads/wave in flight)
    STG3(0, 0, 0); STG3(0, 1, 0); STG3(1, 0, 1); STG3(1, 1, 1);
    VM9;                                  // oldest 3 done -> tile0 kh0 landed
    asm volatile("s_barrier" ::: "memory");

    // one phase: ds_read frags || prefetch issue -> bar -> lgkm0 -> MFMA -> vm -> bar
#define PH(b_, kh_, STG_STMT, VM_STMT)                                             \
    {                                                                              \
        const char* Ab_ = lds + AOF(b_, kh_);                                      \
        const char* Bb_ = lds + BOF(b_, kh_);                                      \
        bf16x8 af_[4], bfr_[4];                                                    \
        _Pragma("unroll")                                                          \
        for (int i_ = 0; i_ < 4; ++i_) {                                           \
            af_[i_]  = *(const bf16x8*)(Ab_ + offA[i_]);                           \
            bfr_[i_] = *(const bf16x8*)(Bb_ + offB[i_]);                           \
        }                                                                          \
        STG_STMT;                                                                  \
        asm volatile("s_barrier" ::: "memory");                                    \
        asm volatile("s_waitcnt lgkmcnt(0)" ::: "memory");                         \
        __builtin_amdgcn_sched_barrier(0);                                         \
        __builtin_amdgcn_s_setprio(1);                                             \
        _Pragma("unroll")                                                          \
        for (int mi_ = 0; mi_ < 4; ++mi_)                                          \
            _Pragma("unroll")                                                      \
            for (int nj_ = 0; nj_ < 4; ++nj_)                                      \
                acc[mi_][nj_] = __builtin_amdgcn_mfma_f32_16x16x32_bf16(           \
                    af_[mi_], bfr_[nj_], acc[mi_][nj_], 0, 0, 0);                  \
        __builtin_amdgcn_s_setprio(0);                                             \
        VM_STMT;                                                                   \
        asm volatile("s_barrier" ::: "memory");                                    \
    }

    // main loop: tiles 0..11 (buffer residues static via unroll-by-3);
    // each phase issues the staging group 2 K-tiles ahead.
    for (int u = 0; u < 12; u += 3) {
        PH(0, 0, STG3(u + 2, 0, 2), VM9);  PH(0, 1, STG3(u + 2, 1, 2), VM9);
        PH(1, 0, STG3(u + 3, 0, 0), VM9);  PH(1, 1, STG3(u + 3, 1, 0), VM9);
        PH(2, 0, STG3(u + 4, 0, 1), VM9);  PH(2, 1, STG3(u + 4, 1, 1), VM9);
    }
    // tiles 12..15 peeled (issues for 14,15; then drain with counted waits)
    PH(0, 0, STG3(14, 0, 2), VM9);  PH(0, 1, STG3(14, 1, 2), VM9);
    PH(1, 0, STG3(15, 0, 0), VM9);  PH(1, 1, STG3(15, 1, 0), VM9);
    PH(2, 0, , VM6);                PH(2, 1, , VM3);
    PH(0, 0, , VM0);                PH(0, 1, , );

#undef PH
#undef STG3
#undef VM9
#undef VM6
#undef VM3
#undef VM0

    // epilogue: C-write (same fragment mapping as verified base kernel)
    const int cr = quad * 4, cc = frow;
#pragma unroll
    for (int mi = 0; mi < 4; ++mi) {
#pragma unroll
        for (int nj = 0; nj < 4; ++nj) {
            CT* Cp = C + (size_t)(m0 + wm * 64 + mi * 16 + cr) * 1024
                       + n0c + wn * 64 + nj * 16 + cc;
#pragma unroll
            for (int r = 0; r < 4; r++) Cp[(size_t)r * 1024] = (CT)acc[mi][nj][r];
        }
    }
}

// Fused QKV: BTall = [WqT|WkT|WvT] as [3072][1024]; QKV = [Q|K|V] contiguous.
// 768 blocks = 32 m-tiles x 24 n-tiles = exactly 3 full rounds on 256 CUs.
// XCD swizzle (T1, bijective: 768 % 8 == 0).
__global__ __launch_bounds__(512, 2) void qkv_gemm_8ph(const __bf16* __restrict__ xb,
                                                       const __bf16* __restrict__ BTall,
                                                       __bf16* __restrict__ QKV) {
    const int id = blockIdx.x;
    const int wg = (id & 7) * 96 + (id >> 3);
    const int mt = wg / 24, nt = wg % 24;
    const int mat = nt >> 3;
    gemm_8ph_body<__bf16>(xb, BTall, QKV + (size_t)mat * NQ,
                          mt * 256, nt * 128, (nt & 7) * 128);
}

// Output projection: 256 blocks = exactly 1 full round.
__global__ __launch_bounds__(512, 2) void out_gemm_8ph(const __bf16* __restrict__ Yb,
                                                       const __bf16* __restrict__ WoT,
                                                       float* __restrict__ Cout) {
    const int id = blockIdx.x;
    const int wg = (id & 7) * 32 + (id >> 3);
    const int mt = wg >> 3, nt = wg & 7;
    gemm_8ph_body<float>(Yb, WoT, Cout, mt * 256, nt * 128, nt * 128);
}

// ---------------------------------------------------------------------------
// Fused gates + x cast (MFMA).  128 blocks x 256 thr; block = 64 rows.
// ---------------------------------------------------------------------------
#define WGS 1032   // lWg row stride (bf16): 516 dw, 4-dw bank rotation
#define LAS 40     // lA row stride (bf16): 20 dw rotation, 16B aligned
__global__ __launch_bounds__(256) void gates_fused(const float* __restrict__ x,
                                                   const float* __restrict__ Wa,
                                                   const float* __restrict__ ba,
                                                   const float* __restrict__ Wb,
                                                   const float* __restrict__ bb,
                                                   float* __restrict__ AlphaT,
                                                   float* __restrict__ BetaT,
                                                   __bf16* __restrict__ xb) {
    __shared__ __align__(16) __bf16 lWg[32 * WGS];
    __shared__ __align__(16) __bf16 lA[64 * LAS];

    const int tid = threadIdx.x;
    const int wid = tid >> 6, lane = tid & 63;
    const int quad = lane >> 4, frow = lane & 15;
    const int m0 = blockIdx.x * 64;

    // ---- stage W^T (bf16) into LDS ----
    {
        const int kbase = tid * 4;
#pragma unroll
        for (int j = 0; j < 4; j++) {
            const int k = kbase + j;
            const float4* war = (const float4*)(Wa + (size_t)k * NH);
            const float4* wbr = (const float4*)(Wb + (size_t)k * NH);
#pragma unroll
            for (int q = 0; q < 4; q++) {
                const float4 a = war[q], bq = wbr[q];
                lWg[(q * 4 + 0) * WGS + k] = (__bf16)a.x;
                lWg[(q * 4 + 1) * WGS + k] = (__bf16)a.y;
                lWg[(q * 4 + 2) * WGS + k] = (__bf16)a.z;
                lWg[(q * 4 + 3) * WGS + k] = (__bf16)a.w;
                lWg[(16 + q * 4 + 0) * WGS + k] = (__bf16)bq.x;
                lWg[(16 + q * 4 + 1) * WGS + k] = (__bf16)bq.y;
                lWg[(16 + q * 4 + 2) * WGS + k] = (__bf16)bq.z;
                lWg[(16 + q * 4 + 3) * WGS + k] = (__bf16)bq.w;
            }
        }
    }
    const float bias_a = ba[frow];
    const float bias_b = bb[frow];

    // ---- pipelined K loop ----
    const int rrow = tid >> 2;          // 0..63
    const int rk   = (tid & 3) * 8;     // 0,8,16,24
    const float* xrow = x + (size_t)(m0 + rrow) * DM + rk;
    float4 c0 = *(const float4*)(xrow + 0);
    float4 c1 = *(const float4*)(xrow + 4);

    f32x4 acc[2];
    acc[0] = (f32x4)0.f; acc[1] = (f32x4)0.f;

    for (int k0 = 0; k0 < DM; k0 += 32) {
        __syncthreads();   // prev iter's lA reads done (also covers lWg stage)
        bf16x8 xv;
        xv[0] = (__bf16)c0.x; xv[1] = (__bf16)c0.y; xv[2] = (__bf16)c0.z; xv[3] = (__bf16)c0.w;
        xv[4] = (__bf16)c1.x; xv[5] = (__bf16)c1.y; xv[6] = (__bf16)c1.z; xv[7] = (__bf16)c1.w;
        *(bf16x8*)&lA[rrow * LAS + rk] = xv;
        *(bf16x8*)(xb + (size_t)(m0 + rrow) * DM + k0 + rk) = xv;
        if (k0 + 32 < DM) {
            c0 = *(const float4*)(xrow + k0 + 32);
            c1 = *(const float4*)(xrow + k0 + 36);
        }
        __syncthreads();
        const bf16x8 af = *(const bf16x8*)&lA[(wid * 16 + frow) * LAS + quad * 8];
#pragma unroll
        for (int ct = 0; ct < 2; ct++) {
            const bf16x8 bf = *(const bf16x8*)&lWg[(ct * 16 + frow) * WGS + k0 + quad * 8];
            acc[ct] = __builtin_amdgcn_mfma_f32_16x16x32_bf16(af, bf, acc[ct], 0, 0, 0);
        }
    }

    // ---- sigmoid epilogue, transposed store ----
#pragma unroll
    for (int ct = 0; ct < 2; ct++) {
        const float bias = (ct == 0) ? bias_a : bias_b;
        float* dst = (ct == 0) ? AlphaT : BetaT;
#pragma unroll
        for (int r = 0; r < 4; r++) {
            const int row = m0 + wid * 16 + quad * 4 + r;
            const float s = acc[ct][r] + bias;
            dst[(size_t)frow * NROWS + row] = 1.f / (1.f + __expf(-s));
        }
    }
}

// ---------------------------------------------------------------------------
// Pass A (MFMA, bf16 I/O): per (b,h,c), 256 threads = 4 waves.
// ---------------------------------------------------------------------------
__global__ __launch_bounds__(256) void chunk_ds(const __bf16* __restrict__ Q,
                                                const __bf16* __restrict__ K,
                                                __bf16* __restrict__ V,
                                                const float* __restrict__ AlphaT,
                                                const float* __restrict__ BetaT,
                                                float* __restrict__ Dec,
                                                float* __restrict__ DS,
                                                float* __restrict__ ExpT) {
    __shared__ __align__(16) __bf16 Qb[64 * 64];
    __shared__ __align__(16) __bf16 Kb[64 * 64];
    __shared__ __align__(16) __bf16 KTs[64 * 64];  // [j][s] = swd_s * kn[s][j]
    __shared__ __align__(16) __bf16 VTb[64 * 64];  // [i][s] = V[s][i]
    __shared__ __align__(16) __bf16 Ab[64 * 64];   // [t][s]
    __shared__ float sla[64], sb[64], swd[64];

    const int blk = blockIdx.x;
    const int c = blk & 31, h = (blk >> 5) & 15, b = blk >> 9;
    const int t0 = c * CH;
    const int tid = threadIdx.x;
    const int wid = tid >> 6, lane = tid & 63;
    const size_t rowbase = ((size_t)(b * T_LEN + t0) * NH + h) * DH;

    // prefetch (16B bf16x8 per matrix per round)
    const int srow = tid >> 3;          // 0..31
    const int scol = (tid & 7) * 8;     // 0..56
    bf16x8 q8[2], k8[2], v8[2];
#pragma unroll
    for (int r = 0; r < 2; r++) {
        const size_t g = rowbase + (size_t)(srow + 32 * r) * INNER + scol;
        q8[r] = *(const bf16x8*)(Q + g);
        k8[r] = *(const bf16x8*)(K + g);
        v8[r] = *(const bf16x8*)(V + g);
    }

    // gates: prefix-sum of log(alpha) over the chunk (wave 0, coalesced)
    if (tid < 64) {
        const int t = tid;
        const size_t gaT = (size_t)h * NROWS + b * T_LEN + t0 + t;
        const float a  = AlphaT[gaT];
        const float bt = BetaT[gaT];
        float xx = logf(a);
#pragma unroll
        for (int off = 1; off < 64; off <<= 1) {
            const float y = __shfl_up(xx, off, 64);
            if (t >= off) xx += y;
        }
        const float la63 = __shfl(xx, 63, 64);
        sla[t] = xx;
        sb[t]  = bt;
        swd[t] = bt * __expf(la63 - xx);
        ExpT[gaT] = __expf(xx);
        if (t == 63) Dec[(size_t)(b * NH + h) * NCH + c] = __expf(la63);
    }
    __syncthreads();

    // stage to LDS: normalize k rows (8 lanes per row -> 3 shfl_xor)
#pragma unroll
    for (int r = 0; r < 2; r++) {
        const int row = srow + 32 * r;
        float kf[8];
        float ss = 0.f;
#pragma unroll
        for (int j = 0; j < 8; j++) { kf[j] = (float)k8[r][j]; ss += kf[j] * kf[j]; }
        ss += __shfl_xor(ss, 1, 64);
        ss += __shfl_xor(ss, 2, 64);
        ss += __shfl_xor(ss, 4, 64);
        const float scale = 1.f / fmaxf(sqrtf(ss), 1e-12f);
        const float w = swd[row];
        bf16x8 kn8;
#pragma unroll
        for (int j = 0; j < 8; j++) {
            const float kn = kf[j] * scale;
            kn8[j] = (__bf16)kn;
            KTs[swz(scol + j, row)] = (__bf16)(w * kn);
            VTb[swz(scol + j, row)] = v8[r][j];
        }
        *(bf16x8*)&Qb[swz(row, scol)] = q8[r];
        *(bf16x8*)&Kb[swz(row, scol)] = kn8;
    }
    __syncthreads();

    const int quad = lane >> 4;
    const int frow = lane & 15;
    const int tw = wid * 16;   // this wave's 16-row output stripe

    // ---- G = Q K^T ----
    f32x4 accG[4];
#pragma unroll
    for (int i = 0; i < 4; i++) accG[i] = (f32x4)0.f;
#pragma unroll
    for (int ks = 0; ks < 2; ks++) {
        const int ko = quad * 8 + 32 * ks;
        const bf16x8 aq = *(const bf16x8*)&Qb[swz(tw + frow, ko)];
#pragma unroll
        for (int st = 0; st < 4; st++) {
            const bf16x8 bk = *(const bf16x8*)&Kb[swz(st * 16 + frow, ko)];
            accG[st] = __builtin_amdgcn_mfma_f32_16x16x32_bf16(aq, bk, accG[st], 0, 0, 0);
        }
    }
    // ---- mask -> Ab (C layout: row=quad*4+r, col=frow) ----
#pragma unroll
    for (int st = 0; st < 4; st++) {
#pragma unroll
        for (int r = 0; r < 4; r++) {
            const int t = tw + quad * 4 + r;
            const int s = st * 16 + frow;
            const float av = (s <= t) ? __expf(sla[t] - sla[s]) * sb[s] * accG[st][r] : 0.f;
            Ab[swz(t, s)] = (__bf16)av;
        }
    }
    __syncthreads();

    // ---- Y_intra = A V  and  dS = VT * KTs^T ----
    f32x4 accY[4], accD[4];
#pragma unroll
    for (int i = 0; i < 4; i++) { accY[i] = (f32x4)0.f; accD[i] = (f32x4)0.f; }
#pragma unroll
    for (int ks = 0; ks < 2; ks++) {
        const int ko = quad * 8 + 32 * ks;
        const bf16x8 aA = *(const bf16x8*)&Ab[swz(tw + frow, ko)];
        const bf16x8 aV = *(const bf16x8*)&VTb[swz(tw + frow, ko)];
#pragma unroll
        for (int jt = 0; jt < 4; jt++) {
            const bf16x8 bv = *(const bf16x8*)&VTb[swz(jt * 16 + frow, ko)];
            const bf16x8 bk = *(const bf16x8*)&KTs[swz(jt * 16 + frow, ko)];
            accY[jt] = __builtin_amdgcn_mfma_f32_16x16x32_bf16(aA, bv, accY[jt], 0, 0, 0);
            accD[jt] = __builtin_amdgcn_mfma_f32_16x16x32_bf16(aV, bk, accD[jt], 0, 0, 0);
        }
    }
    // write Y_intra (bf16) over V, dS (fp32) to DS
#pragma unroll
    for (int jt = 0; jt < 4; jt++) {
#pragma unroll
        for (int r = 0; r < 4; r++) {
            const int row = tw + quad * 4 + r;
            const size_t g = rowbase + (size_t)row * INNER + jt * 16 + frow;
            V[g]  = (__bf16)accY[jt][r];
            DS[g] = accD[jt][r];
        }
    }
}

// ---------------------------------------------------------------------------
// Pass B1 (serial, tiny): S_{c+1} = Dec_c * S_c + dS_c over 32 chunks per
// (b,h).  Writes each PRE-update state S_c as bf16 to ScB (for chunk_y).
// ---------------------------------------------------------------------------
__global__ __launch_bounds__(256) void chunk_state(const float* __restrict__ DS,
                                                   const float* __restrict__ Dec,
                                                   const float* __restrict__ state_in,
                                                   float* __restrict__ state_out,
                                                   __bf16* __restrict__ ScB) {
    const int blk = blockIdx.x;          // (b,h)
    const int b = blk >> 4, h = blk & 15;
    const int tid = threadIdx.x;
    const int w = tid >> 6;
    const int l = tid & 63;

    float S[16];
    {
        const float* st = state_in + ((size_t)(b * NH + h) * DH + l) * DH + 16 * w;
#pragma unroll
        for (int j4 = 0; j4 < 4; j4++)
            *(float4*)&S[4 * j4] = *(const float4*)(st + 4 * j4);
    }

    for (int c = 0; c < NCH; c++) {
        const int t0 = c * CH;
        const float decay = Dec[(size_t)(b * NH + h) * NCH + c];
        const size_t off = ((size_t)(b * T_LEN + t0 + l) * NH + h) * DH + 16 * w;
        const float* ds = DS + off;
        __bf16* sc = ScB + off;
        float4 dv[4];
#pragma unroll
        for (int j4 = 0; j4 < 4; j4++) dv[j4] = *(const float4*)(ds + 4 * j4);
#pragma unroll
        for (int j4 = 0; j4 < 4; j4++) {
            bf16x4 o;
            o[0] = (__bf16)S[4 * j4 + 0]; o[1] = (__bf16)S[4 * j4 + 1];
            o[2] = (__bf16)S[4 * j4 + 2]; o[3] = (__bf16)S[4 * j4 + 3];
            *(bf16x4*)(sc + 4 * j4) = o;
        }
#pragma unroll
        for (int j4 = 0; j4 < 4; j4++) {
            S[4 * j4 + 0] = decay * S[4 * j4 + 0] + dv[j4].x;
            S[4 * j4 + 1] = decay * S[4 * j4 + 1] + dv[j4].y;
            S[4 * j4 + 2] = decay * S[4 * j4 + 2] + dv[j4].z;
            S[4 * j4 + 3] = decay * S[4 * j4 + 3] + dv[j4].w;
        }
    }

    float* so = state_out + ((size_t)(b * NH + h) * DH + l) * DH + 16 * w;
#pragma unroll
    for (int j4 = 0; j4 < 4; j4++)
        *(float4*)(so + 4 * j4) = *(const float4*)&S[4 * j4];
}

// ---------------------------------------------------------------------------
// Pass B2 (MFMA): Yb[t][i] = bf16( Yb[t][i] + ExpT[t]*sum_j Q[t][j]Sc[i][j] )
// ---------------------------------------------------------------------------
__global__ __launch_bounds__(256) void chunk_y(const __bf16* __restrict__ Q,
                                               const __bf16* __restrict__ ScB,
                                               __bf16* __restrict__ Yb,
                                               const float* __restrict__ ExpT) {
    __shared__ __align__(16) __bf16 Qb[64 * 64];
    __shared__ __align__(16) __bf16 Scb[64 * 64];
    __shared__ float sexp[64];

    const int blk = blockIdx.x;
    const int c = blk & 31, h = (blk >> 5) & 15, b = blk >> 9;
    const int t0 = c * CH;
    const int tid = threadIdx.x;
    const int wid = tid >> 6, lane = tid & 63;
    const size_t rowbase = ((size_t)(b * T_LEN + t0) * NH + h) * DH;

    // prefetch Q / Sc (bf16x8)
    const int srow = tid >> 3;
    const int scol = (tid & 7) * 8;
    bf16x8 q8[2], s8[2];
#pragma unroll
    for (int r = 0; r < 2; r++) {
        const size_t g = rowbase + (size_t)(srow + 32 * r) * INNER + scol;
        q8[r] = *(const bf16x8*)(Q + g);
        s8[r] = *(const bf16x8*)(ScB + g);
    }

    if (tid < 64)
        sexp[tid] = ExpT[(size_t)h * NROWS + b * T_LEN + t0 + tid];

#pragma unroll
    for (int r = 0; r < 2; r++) {
        *(bf16x8*)&Qb[swz(srow + 32 * r, scol)]  = q8[r];
        *(bf16x8*)&Scb[swz(srow + 32 * r, scol)] = s8[r];
    }
    __syncthreads();

    const int quad = lane >> 4;
    const int frow = lane & 15;
    const int tw = wid * 16;

    f32x4 accU[4];
#pragma unroll
    for (int i = 0; i < 4; i++) accU[i] = (f32x4)0.f;
#pragma unroll
    for (int ks = 0; ks < 2; ks++) {
        const int ko = quad * 8 + 32 * ks;
        const bf16x8 aq = *(const bf16x8*)&Qb[swz(tw + frow, ko)];
#pragma unroll
        for (int it = 0; it < 4; it++) {
            const bf16x8 bs = *(const bf16x8*)&Scb[swz(it * 16 + frow, ko)];
            accU[it] = __builtin_amdgcn_mfma_f32_16x16x32_bf16(aq, bs, accU[it], 0, 0, 0);
        }
    }

#pragma unroll
    for (int it = 0; it < 4; it++) {
#pragma unroll
        for (int r = 0; r < 4; r++) {
            const int t = tw + quad * 4 + r;
            const size_t g = rowbase + (size_t)t * INNER + it * 16 + frow;
            Yb[g] = (__bf16)(sexp[t] * accU[it][r] + (float)Yb[g]);
        }
    }
}

// ---------------------------------------------------------------------------
extern "C" void kernel_launch(void* const* d_in, const int* in_sizes, int n_in,
                              void* d_out, int out_size, void* d_ws, size_t ws_size,
                              hipStream_t stream) {
    const float* x     = (const float*)d_in[0];
    const float* state = (const float*)d_in[1];
    const float* Wq    = (const float*)d_in[2];
    const float* Wk    = (const float*)d_in[3];
    const float* Wv    = (const float*)d_in[4];
    const float* Wa    = (const float*)d_in[5];
    const float* ba    = (const float*)d_in[6];
    const float* Wb    = (const float*)d_in[7];
    const float* bb    = (const float*)d_in[8];
    const float* Wo    = (const float*)d_in[9];

    __bf16* Qb    = (__bf16*)d_ws;               // NQ bf16 (raw q, preserved)
    __bf16* Kbf   = Qb + (size_t)NQ;             // NQ bf16 (raw k)
    __bf16* Vbf   = Kbf + (size_t)NQ;            // NQ bf16 (v -> Y_intra -> Y)
    float*  DS    = (float*)(Vbf + (size_t)NQ);  // NQ fp32 (dS)
    float*  AlphaT= DS + (size_t)NQ;             // [NH][NROWS]
    float*  BetaT = AlphaT + (size_t)NROWS * NH;
    float*  ExpT  = BetaT + (size_t)NROWS * NH;  // [NH][NROWS] exp(la_t)
    float*  Dec   = ExpT + (size_t)NROWS * NH;   // per-chunk decay
    __bf16* xb    = (__bf16*)(Dec + (size_t)B_SZ * NH * NCH);
    __bf16* ScB   = xb;                          // reuse: xb dead after qkv gemm
    __bf16* WqT   = xb + (size_t)NQ;             // [WqT|WkT|WvT] contiguous
    __bf16* WkT   = WqT + (size_t)DM * INNER;
    __bf16* WvT   = WkT + (size_t)DM * INNER;
    __bf16* WoT   = WvT + (size_t)DM * INNER;

    float* out  = (float*)d_out;                // (B,T,DM)
    float* Sout = out + (size_t)NQ;             // (B,H,D,D)

    // 0) weights cast+transpose
    wt_cast_transpose<<<dim3(16, 16, 4), 256, 0, stream>>>(Wq, Wk, Wv, Wo,
                                                           WqT, WkT, WvT, WoT);
    // 1) fused gates (MFMA) + x->bf16 cast
    gates_fused<<<NROWS / 64, 256, 0, stream>>>(x, Wa, ba, Wb, bb,
                                                AlphaT, BetaT, xb);
    // 2) Q/K/V projections fused into ONE 3-stage-pipelined GEMM
    //    (M=8192, N=3072): 768 blocks = exactly 3 full rounds on 256 CUs.
    qkv_gemm_8ph<<<768, 512, 0, stream>>>(xb, WqT, Qb);
    // 3) intra-chunk MFMA (+fused knorm): Y_intra -> Vbf, dS -> DS
    chunk_ds<<<B_SZ * NH * NCH, 256, 0, stream>>>(Qb, Kbf, Vbf, AlphaT, BetaT,
                                                  Dec, DS, ExpT);
    // 4) serial inter-chunk state recurrence; Sc -> ScB (bf16)
    chunk_state<<<B_SZ * NH, 256, 0, stream>>>(DS, Dec, state, Sout, ScB);
    // 5) parallel Y_inter MFMA, in-place finalize of Vbf
    chunk_y<<<B_SZ * NH * NCH, 256, 0, stream>>>(Qb, ScB, Vbf, ExpT);
    // 6) output projection (3-stage-pipelined, 256 blocks = 1 full round)
    out_gemm_8ph<<<256, 512, 0, stream>>>(Vbf, WoT, out);
}

// Round 3
// 278.635 us; speedup vs baseline: 1.0485x; 1.0302x over previous
//
#include <hip/hip_runtime.h>
#include <hip/hip_bf16.h>
#include <math.h>

// Problem constants
#define B_SZ   4
#define T_LEN  2048
#define DM     1024
#define NH     16
#define DH     64
#define INNER  1024          // NH*DH
#define NROWS  (B_SZ*T_LEN)  // 8192
#define NQ     (NROWS*INNER) // elements per Q/K/V/Y buffer
#define CH     64            // chunk length
#define NCH    (T_LEN/CH)    // 32 chunks

typedef __bf16 bf16x8 __attribute__((ext_vector_type(8)));
typedef __bf16 bf16x4 __attribute__((ext_vector_type(4)));
typedef float  f32x4  __attribute__((ext_vector_type(4)));
typedef __attribute__((address_space(3))) void*       lds_vp;
typedef const __attribute__((address_space(1))) void* gbl_vp;

// Swizzled index into a 64x64 bf16 LDS tile: 8-elem blocks rotated by row>>2.
__device__ __forceinline__ int swz(int row, int col) {
    return (row << 6) + ((((col >> 3) + (row >> 2)) & 7) << 3) + (col & 7);
}

// ---------------------------------------------------------------------------
// Weight transpose + cast: W (K x N fp32, row-major) -> WT (N x K bf16).
// ---------------------------------------------------------------------------
__global__ __launch_bounds__(256) void wt_cast_transpose(const float* __restrict__ Wq,
                                                         const float* __restrict__ Wk,
                                                         const float* __restrict__ Wv,
                                                         const float* __restrict__ Wo,
                                                         __bf16* __restrict__ WqT,
                                                         __bf16* __restrict__ WkT,
                                                         __bf16* __restrict__ WvT,
                                                         __bf16* __restrict__ WoT) {
    __shared__ float tile[64][65];
    const float* W;
    __bf16* WT;
    if      (blockIdx.z == 0) { W = Wq; WT = WqT; }
    else if (blockIdx.z == 1) { W = Wk; WT = WkT; }
    else if (blockIdx.z == 2) { W = Wv; WT = WvT; }
    else                      { W = Wo; WT = WoT; }

    const int k0 = blockIdx.y * 64, n0 = blockIdx.x * 64;
    const int tr  = threadIdx.x >> 4;        // 0..15
    const int tc4 = (threadIdx.x & 15) * 4;  // 0..60

#pragma unroll
    for (int r = 0; r < 4; r++) {
        const int k = tr + 16 * r;
        const float4 v = *(const float4*)(W + (size_t)(k0 + k) * DM + n0 + tc4);
        tile[k][tc4 + 0] = v.x;
        tile[k][tc4 + 1] = v.y;
        tile[k][tc4 + 2] = v.z;
        tile[k][tc4 + 3] = v.w;
    }
    __syncthreads();
#pragma unroll
    for (int r = 0; r < 4; r++) {
        const int n = tr + 16 * r;
        bf16x4 o;
#pragma unroll
        for (int j = 0; j < 4; j++) o[j] = (__bf16)tile[tc4 + j][n];
        *(bf16x4*)(WT + (size_t)(n0 + n) * DM + k0 + tc4) = o;
    }
}

// ---------------------------------------------------------------------------
// 3-stage pipelined bf16 MFMA GEMM, fragment-reuse geometry.
//   C[m0:+256][n0c:+128] = A[m0:+256][0:1024] * BT[n0bt:+128][0:1024]^T
//   256 threads = 4 waves (2M x 2N), per-wave 128x64 output (acc 8x4):
//     12 ds_read_b128 per 32 MFMA = 0.375 reads/MFMA (was 0.5) -- the
//     LDS-read instruction pipe (12 cy/b128/CU, m134) was the bound.
//   LDS: 3 stages x (A 256x32 + B 128x32) bf16 = 72 KiB -> 2 blocks/CU;
//   independent block barriers let one block's MFMA overlap the other's
//   staging (m114 co-scheduling).  Counted vmcnt(6) per phase keeps one
//   full staging group in flight across barriers (T4); lead = 2 phases.
//   Bank swizzle on BOTH sides (pre-swizzled global source + swizzled
//   ds_read offsets, rule 21); residual 2-way conflict is free (m136).
// ---------------------------------------------------------------------------
#define STAGE_STRIDE 24576          // A 16384 + B 8192 bytes
#define B_BASE 16384

template <typename CT>
__device__ __forceinline__ void gemm_pipe_body(const __bf16* __restrict__ A,
                                               const __bf16* __restrict__ BT,
                                               CT* __restrict__ C,
                                               int m0, int n0bt, int n0c) {
    __shared__ __align__(16) char lds[3 * STAGE_STRIDE];

    const int tid  = threadIdx.x;
    const int wid  = tid >> 6;       // 0..3
    const int lane = tid & 63;
    const int wm = wid >> 1;         // 0..1 : 128-row stripe
    const int wn = wid & 1;          // 0..1 : 64-col stripe
    const int frow = lane & 15, quad = lane >> 4;

    // swizzled ds_read byte offsets within one stage (loop-invariant)
    int offA[8], offB[4];
#pragma unroll
    for (int i = 0; i < 8; ++i) {
        const int ra = wm * 128 + i * 16 + frow;
        offA[i] = ra * 64 + ((quad ^ ((ra >> 1) & 3)) << 4);
    }
#pragma unroll
    for (int j = 0; j < 4; ++j) {
        const int rb = wn * 64 + j * 16 + frow;
        offB[j] = B_BASE + rb * 64 + ((quad ^ ((rb >> 1) & 3)) << 4);
    }

    // staging: per-lane pre-swizzled global source (16 rows x 64B per instr)
    const int lr = lane >> 2;                                  // row in region
    const int cs = ((lane & 3) ^ ((lane >> 3) & 3)) << 3;      // elem col (swz)
    const __bf16* gA[4];
#pragma unroll
    for (int q = 0; q < 4; ++q)
        gA[q] = A + (size_t)(m0 + wid * 64 + q * 16 + lr) * 1024 + cs;
    const __bf16* gB[2];
#pragma unroll
    for (int q = 0; q < 2; ++q)
        gB[q] = BT + (size_t)(n0bt + wid * 32 + q * 16 + lr) * 1024 + cs;

    // one staging group: 6 global_load_lds per wave (4 A + 2 B regions)
#define STG(t_, b_) do {                                                           \
        _Pragma("unroll")                                                          \
        for (int q_ = 0; q_ < 4; ++q_)                                             \
            __builtin_amdgcn_global_load_lds((gbl_vp)(gA[q_] + (size_t)(t_) * 32), \
                (lds_vp)(lds + (b_) * STAGE_STRIDE + (wid * 64 + q_ * 16) * 64),   \
                16, 0, 0);                                                         \
        _Pragma("unroll")                                                          \
        for (int q_ = 0; q_ < 2; ++q_)                                             \
            __builtin_amdgcn_global_load_lds((gbl_vp)(gB[q_] + (size_t)(t_) * 32), \
                (lds_vp)(lds + (b_) * STAGE_STRIDE + B_BASE + (wid * 32 + q_ * 16) * 64), \
                16, 0, 0);                                                         \
    } while (0)

#define VM6 asm volatile("s_waitcnt vmcnt(6)" ::: "memory")
#define VM0 asm volatile("s_waitcnt vmcnt(0)" ::: "memory")

    f32x4 acc[8][4];
#pragma unroll
    for (int i = 0; i < 8; i++)
#pragma unroll
        for (int j = 0; j < 4; j++) acc[i][j] = (f32x4)0.f;

    // prologue: stage K-tiles 0,1 (12 loads/wave in flight); wait tile 0
    STG(0, 0); STG(1, 1);
    VM6;
    asm volatile("s_barrier" ::: "memory");

    // one phase: ds_read frags || prefetch issue -> bar -> lgkm0 -> MFMA -> vm -> bar
#define PH(b_, STG_STMT, VM_STMT)                                                  \
    {                                                                              \
        const char* Sb_ = lds + (b_) * STAGE_STRIDE;                               \
        bf16x8 af_[8], bfr_[4];                                                    \
        _Pragma("unroll")                                                          \
        for (int i_ = 0; i_ < 8; ++i_) af_[i_]  = *(const bf16x8*)(Sb_ + offA[i_]);\
        _Pragma("unroll")                                                          \
        for (int j_ = 0; j_ < 4; ++j_) bfr_[j_] = *(const bf16x8*)(Sb_ + offB[j_]);\
        STG_STMT;                                                                  \
        asm volatile("s_barrier" ::: "memory");                                    \
        asm volatile("s_waitcnt lgkmcnt(0)" ::: "memory");                         \
        __builtin_amdgcn_sched_barrier(0);                                         \
        __builtin_amdgcn_s_setprio(1);                                             \
        _Pragma("unroll")                                                          \
        for (int mi_ = 0; mi_ < 8; ++mi_)                                          \
            _Pragma("unroll")                                                      \
            for (int nj_ = 0; nj_ < 4; ++nj_)                                      \
                acc[mi_][nj_] = __builtin_amdgcn_mfma_f32_16x16x32_bf16(           \
                    af_[mi_], bfr_[nj_], acc[mi_][nj_], 0, 0, 0);                  \
        __builtin_amdgcn_s_setprio(0);                                             \
        VM_STMT;                                                                   \
        asm volatile("s_barrier" ::: "memory");                                    \
    }

    // main loop: phases 0..29 (buffer residues static via unroll-by-3);
    // phase p issues the staging group for K-tile p+2.
    for (int u = 0; u < 10; ++u) {
        const int p = 3 * u;
        PH(0, STG(p + 2, 2), VM6);
        PH(1, STG(p + 3, 0), VM6);
        PH(2, STG(p + 4, 1), VM6);
    }
    // phases 30,31: drain
    PH(0, , VM0);
    PH(1, , );

#undef PH
#undef STG
#undef VM6
#undef VM0

    // epilogue: C-write (same fragment mapping as verified base kernel)
    const int cr = quad * 4, cc = frow;
#pragma unroll
    for (int mi = 0; mi < 8; ++mi) {
#pragma unroll
        for (int nj = 0; nj < 4; ++nj) {
            CT* Cp = C + (size_t)(m0 + wm * 128 + mi * 16 + cr) * 1024
                       + n0c + wn * 64 + nj * 16 + cc;
#pragma unroll
            for (int r = 0; r < 4; r++) Cp[(size_t)r * 1024] = (CT)acc[mi][nj][r];
        }
    }
}

// Fused QKV: BTall = [WqT|WkT|WvT] as [3072][1024]; QKV = [Q|K|V] contiguous.
// 768 blocks = 32 m-tiles x 24 n-tiles; 2 blocks/CU resident.
// XCD swizzle (T1, bijective: 768 % 8 == 0).
__global__ __launch_bounds__(256, 2) void qkv_gemm_8ph(const __bf16* __restrict__ xb,
                                                       const __bf16* __restrict__ BTall,
                                                       __bf16* __restrict__ QKV) {
    const int id = blockIdx.x;
    const int wg = (id & 7) * 96 + (id >> 3);
    const int mt = wg / 24, nt = wg % 24;
    const int mat = nt >> 3;
    gemm_pipe_body<__bf16>(xb, BTall, QKV + (size_t)mat * NQ,
                           mt * 256, nt * 128, (nt & 7) * 128);
}

// Output projection: 256 blocks (32 m x 8 n), all co-resident.
__global__ __launch_bounds__(256, 2) void out_gemm_8ph(const __bf16* __restrict__ Yb,
                                                       const __bf16* __restrict__ WoT,
                                                       float* __restrict__ Cout) {
    const int id = blockIdx.x;
    const int wg = (id & 7) * 32 + (id >> 3);
    const int mt = wg >> 3, nt = wg & 7;
    gemm_pipe_body<float>(Yb, WoT, Cout, mt * 256, nt * 128, nt * 128);
}

// ---------------------------------------------------------------------------
// Fused gates + x cast (MFMA).  128 blocks x 256 thr; block = 64 rows.
// ---------------------------------------------------------------------------
#define WGS 1032   // lWg row stride (bf16): 516 dw, 4-dw bank rotation
#define LAS 40     // lA row stride (bf16): 20 dw rotation, 16B aligned
__global__ __launch_bounds__(256) void gates_fused(const float* __restrict__ x,
                                                   const float* __restrict__ Wa,
                                                   const float* __restrict__ ba,
                                                   const float* __restrict__ Wb,
                                                   const float* __restrict__ bb,
                                                   float* __restrict__ AlphaT,
                                                   float* __restrict__ BetaT,
                                                   __bf16* __restrict__ xb) {
    __shared__ __align__(16) __bf16 lWg[32 * WGS];
    __shared__ __align__(16) __bf16 lA[64 * LAS];

    const int tid = threadIdx.x;
    const int wid = tid >> 6, lane = tid & 63;
    const int quad = lane >> 4, frow = lane & 15;
    const int m0 = blockIdx.x * 64;

    // ---- stage W^T (bf16) into LDS ----
    {
        const int kbase = tid * 4;
#pragma unroll
        for (int j = 0; j < 4; j++) {
            const int k = kbase + j;
            const float4* war = (const float4*)(Wa + (size_t)k * NH);
            const float4* wbr = (const float4*)(Wb + (size_t)k * NH);
#pragma unroll
            for (int q = 0; q < 4; q++) {
                const float4 a = war[q], bq = wbr[q];
                lWg[(q * 4 + 0) * WGS + k] = (__bf16)a.x;
                lWg[(q * 4 + 1) * WGS + k] = (__bf16)a.y;
                lWg[(q * 4 + 2) * WGS + k] = (__bf16)a.z;
                lWg[(q * 4 + 3) * WGS + k] = (__bf16)a.w;
                lWg[(16 + q * 4 + 0) * WGS + k] = (__bf16)bq.x;
                lWg[(16 + q * 4 + 1) * WGS + k] = (__bf16)bq.y;
                lWg[(16 + q * 4 + 2) * WGS + k] = (__bf16)bq.z;
                lWg[(16 + q * 4 + 3) * WGS + k] = (__bf16)bq.w;
            }
        }
    }
    const float bias_a = ba[frow];
    const float bias_b = bb[frow];

    // ---- pipelined K loop ----
    const int rrow = tid >> 2;          // 0..63
    const int rk   = (tid & 3) * 8;     // 0,8,16,24
    const float* xrow = x + (size_t)(m0 + rrow) * DM + rk;
    float4 c0 = *(const float4*)(xrow + 0);
    float4 c1 = *(const float4*)(xrow + 4);

    f32x4 acc[2];
    acc[0] = (f32x4)0.f; acc[1] = (f32x4)0.f;

    for (int k0 = 0; k0 < DM; k0 += 32) {
        __syncthreads();   // prev iter's lA reads done (also covers lWg stage)
        bf16x8 xv;
        xv[0] = (__bf16)c0.x; xv[1] = (__bf16)c0.y; xv[2] = (__bf16)c0.z; xv[3] = (__bf16)c0.w;
        xv[4] = (__bf16)c1.x; xv[5] = (__bf16)c1.y; xv[6] = (__bf16)c1.z; xv[7] = (__bf16)c1.w;
        *(bf16x8*)&lA[rrow * LAS + rk] = xv;
        *(bf16x8*)(xb + (size_t)(m0 + rrow) * DM + k0 + rk) = xv;
        if (k0 + 32 < DM) {
            c0 = *(const float4*)(xrow + k0 + 32);
            c1 = *(const float4*)(xrow + k0 + 36);
        }
        __syncthreads();
        const bf16x8 af = *(const bf16x8*)&lA[(wid * 16 + frow) * LAS + quad * 8];
#pragma unroll
        for (int ct = 0; ct < 2; ct++) {
            const bf16x8 bf = *(const bf16x8*)&lWg[(ct * 16 + frow) * WGS + k0 + quad * 8];
            acc[ct] = __builtin_amdgcn_mfma_f32_16x16x32_bf16(af, bf, acc[ct], 0, 0, 0);
        }
    }

    // ---- sigmoid epilogue, transposed store ----
#pragma unroll
    for (int ct = 0; ct < 2; ct++) {
        const float bias = (ct == 0) ? bias_a : bias_b;
        float* dst = (ct == 0) ? AlphaT : BetaT;
#pragma unroll
        for (int r = 0; r < 4; r++) {
            const int row = m0 + wid * 16 + quad * 4 + r;
            const float s = acc[ct][r] + bias;
            dst[(size_t)frow * NROWS + row] = 1.f / (1.f + __expf(-s));
        }
    }
}

// ---------------------------------------------------------------------------
// Pass A (MFMA, bf16 I/O): per (b,h,c), 256 threads = 4 waves.
// ---------------------------------------------------------------------------
__global__ __launch_bounds__(256) void chunk_ds(const __bf16* __restrict__ Q,
                                                const __bf16* __restrict__ K,
                                                __bf16* __restrict__ V,
                                                const float* __restrict__ AlphaT,
                                                const float* __restrict__ BetaT,
                                                float* __restrict__ Dec,
                                                float* __restrict__ DS,
                                                float* __restrict__ ExpT) {
    __shared__ __align__(16) __bf16 Qb[64 * 64];
    __shared__ __align__(16) __bf16 Kb[64 * 64];
    __shared__ __align__(16) __bf16 KTs[64 * 64];  // [j][s] = swd_s * kn[s][j]
    __shared__ __align__(16) __bf16 VTb[64 * 64];  // [i][s] = V[s][i]
    __shared__ __align__(16) __bf16 Ab[64 * 64];   // [t][s]
    __shared__ float sla[64], sb[64], swd[64];

    const int blk = blockIdx.x;
    const int c = blk & 31, h = (blk >> 5) & 15, b = blk >> 9;
    const int t0 = c * CH;
    const int tid = threadIdx.x;
    const int wid = tid >> 6, lane = tid & 63;
    const size_t rowbase = ((size_t)(b * T_LEN + t0) * NH + h) * DH;

    // prefetch (16B bf16x8 per matrix per round)
    const int srow = tid >> 3;          // 0..31
    const int scol = (tid & 7) * 8;     // 0..56
    bf16x8 q8[2], k8[2], v8[2];
#pragma unroll
    for (int r = 0; r < 2; r++) {
        const size_t g = rowbase + (size_t)(srow + 32 * r) * INNER + scol;
        q8[r] = *(const bf16x8*)(Q + g);
        k8[r] = *(const bf16x8*)(K + g);
        v8[r] = *(const bf16x8*)(V + g);
    }

    // gates: prefix-sum of log(alpha) over the chunk (wave 0, coalesced)
    if (tid < 64) {
        const int t = tid;
        const size_t gaT = (size_t)h * NROWS + b * T_LEN + t0 + t;
        const float a  = AlphaT[gaT];
        const float bt = BetaT[gaT];
        float xx = logf(a);
#pragma unroll
        for (int off = 1; off < 64; off <<= 1) {
            const float y = __shfl_up(xx, off, 64);
            if (t >= off) xx += y;
        }
        const float la63 = __shfl(xx, 63, 64);
        sla[t] = xx;
        sb[t]  = bt;
        swd[t] = bt * __expf(la63 - xx);
        ExpT[gaT] = __expf(xx);
        if (t == 63) Dec[(size_t)(b * NH + h) * NCH + c] = __expf(la63);
    }
    __syncthreads();

    // stage to LDS: normalize k rows (8 lanes per row -> 3 shfl_xor)
#pragma unroll
    for (int r = 0; r < 2; r++) {
        const int row = srow + 32 * r;
        float kf[8];
        float ss = 0.f;
#pragma unroll
        for (int j = 0; j < 8; j++) { kf[j] = (float)k8[r][j]; ss += kf[j] * kf[j]; }
        ss += __shfl_xor(ss, 1, 64);
        ss += __shfl_xor(ss, 2, 64);
        ss += __shfl_xor(ss, 4, 64);
        const float scale = 1.f / fmaxf(sqrtf(ss), 1e-12f);
        const float w = swd[row];
        bf16x8 kn8;
#pragma unroll
        for (int j = 0; j < 8; j++) {
            const float kn = kf[j] * scale;
            kn8[j] = (__bf16)kn;
            KTs[swz(scol + j, row)] = (__bf16)(w * kn);
            VTb[swz(scol + j, row)] = v8[r][j];
        }
        *(bf16x8*)&Qb[swz(row, scol)] = q8[r];
        *(bf16x8*)&Kb[swz(row, scol)] = kn8;
    }
    __syncthreads();

    const int quad = lane >> 4;
    const int frow = lane & 15;
    const int tw = wid * 16;   // this wave's 16-row output stripe

    // ---- G = Q K^T ----
    f32x4 accG[4];
#pragma unroll
    for (int i = 0; i < 4; i++) accG[i] = (f32x4)0.f;
#pragma unroll
    for (int ks = 0; ks < 2; ks++) {
        const int ko = quad * 8 + 32 * ks;
        const bf16x8 aq = *(const bf16x8*)&Qb[swz(tw + frow, ko)];
#pragma unroll
        for (int st = 0; st < 4; st++) {
            const bf16x8 bk = *(const bf16x8*)&Kb[swz(st * 16 + frow, ko)];
            accG[st] = __builtin_amdgcn_mfma_f32_16x16x32_bf16(aq, bk, accG[st], 0, 0, 0);
        }
    }
    // ---- mask -> Ab (C layout: row=quad*4+r, col=frow) ----
#pragma unroll
    for (int st = 0; st < 4; st++) {
#pragma unroll
        for (int r = 0; r < 4; r++) {
            const int t = tw + quad * 4 + r;
            const int s = st * 16 + frow;
            const float av = (s <= t) ? __expf(sla[t] - sla[s]) * sb[s] * accG[st][r] : 0.f;
            Ab[swz(t, s)] = (__bf16)av;
        }
    }
    __syncthreads();

    // ---- Y_intra = A V  and  dS = VT * KTs^T ----
    f32x4 accY[4], accD[4];
#pragma unroll
    for (int i = 0; i < 4; i++) { accY[i] = (f32x4)0.f; accD[i] = (f32x4)0.f; }
#pragma unroll
    for (int ks = 0; ks < 2; ks++) {
        const int ko = quad * 8 + 32 * ks;
        const bf16x8 aA = *(const bf16x8*)&Ab[swz(tw + frow, ko)];
        const bf16x8 aV = *(const bf16x8*)&VTb[swz(tw + frow, ko)];
#pragma unroll
        for (int jt = 0; jt < 4; jt++) {
            const bf16x8 bv = *(const bf16x8*)&VTb[swz(jt * 16 + frow, ko)];
            const bf16x8 bk = *(const bf16x8*)&KTs[swz(jt * 16 + frow, ko)];
            accY[jt] = __builtin_amdgcn_mfma_f32_16x16x32_bf16(aA, bv, accY[jt], 0, 0, 0);
            accD[jt] = __builtin_amdgcn_mfma_f32_16x16x32_bf16(aV, bk, accD[jt], 0, 0, 0);
        }
    }
    // write Y_intra (bf16) over V, dS (fp32) to DS
#pragma unroll
    for (int jt = 0; jt < 4; jt++) {
#pragma unroll
        for (int r = 0; r < 4; r++) {
            const int row = tw + quad * 4 + r;
            const size_t g = rowbase + (size_t)row * INNER + jt * 16 + frow;
            V[g]  = (__bf16)accY[jt][r];
            DS[g] = accD[jt][r];
        }
    }
}

// ---------------------------------------------------------------------------
// Pass B1 (serial, tiny): S_{c+1} = Dec_c * S_c + dS_c over 32 chunks per
// (b,h).  Writes each PRE-update state S_c as bf16 to ScB (for chunk_y).
// ---------------------------------------------------------------------------
__global__ __launch_bounds__(256) void chunk_state(const float* __restrict__ DS,
                                                   const float* __restrict__ Dec,
                                                   const float* __restrict__ state_in,
                                                   float* __restrict__ state_out,
                                                   __bf16* __restrict__ ScB) {
    const int blk = blockIdx.x;          // (b,h)
    const int b = blk >> 4, h = blk & 15;
    const int tid = threadIdx.x;
    const int w = tid >> 6;
    const int l = tid & 63;

    float S[16];
    {
        const float* st = state_in + ((size_t)(b * NH + h) * DH + l) * DH + 16 * w;
#pragma unroll
        for (int j4 = 0; j4 < 4; j4++)
            *(float4*)&S[4 * j4] = *(const float4*)(st + 4 * j4);
    }

    for (int c = 0; c < NCH; c++) {
        const int t0 = c * CH;
        const float decay = Dec[(size_t)(b * NH + h) * NCH + c];
        const size_t off = ((size_t)(b * T_LEN + t0 + l) * NH + h) * DH + 16 * w;
        const float* ds = DS + off;
        __bf16* sc = ScB + off;
        float4 dv[4];
#pragma unroll
        for (int j4 = 0; j4 < 4; j4++) dv[j4] = *(const float4*)(ds + 4 * j4);
#pragma unroll
        for (int j4 = 0; j4 < 4; j4++) {
            bf16x4 o;
            o[0] = (__bf16)S[4 * j4 + 0]; o[1] = (__bf16)S[4 * j4 + 1];
            o[2] = (__bf16)S[4 * j4 + 2]; o[3] = (__bf16)S[4 * j4 + 3];
            *(bf16x4*)(sc + 4 * j4) = o;
        }
#pragma unroll
        for (int j4 = 0; j4 < 4; j4++) {
            S[4 * j4 + 0] = decay * S[4 * j4 + 0] + dv[j4].x;
            S[4 * j4 + 1] = decay * S[4 * j4 + 1] + dv[j4].y;
            S[4 * j4 + 2] = decay * S[4 * j4 + 2] + dv[j4].z;
            S[4 * j4 + 3] = decay * S[4 * j4 + 3] + dv[j4].w;
        }
    }

    float* so = state_out + ((size_t)(b * NH + h) * DH + l) * DH + 16 * w;
#pragma unroll
    for (int j4 = 0; j4 < 4; j4++)
        *(float4*)(so + 4 * j4) = *(const float4*)&S[4 * j4];
}

// ---------------------------------------------------------------------------
// Pass B2 (MFMA): Yb[t][i] = bf16( Yb[t][i] + ExpT[t]*sum_j Q[t][j]Sc[i][j] )
// ---------------------------------------------------------------------------
__global__ __launch_bounds__(256) void chunk_y(const __bf16* __restrict__ Q,
                                               const __bf16* __restrict__ ScB,
                                               __bf16* __restrict__ Yb,
                                               const float* __restrict__ ExpT) {
    __shared__ __align__(16) __bf16 Qb[64 * 64];
    __shared__ __align__(16) __bf16 Scb[64 * 64];
    __shared__ float sexp[64];

    const int blk = blockIdx.x;
    const int c = blk & 31, h = (blk >> 5) & 15, b = blk >> 9;
    const int t0 = c * CH;
    const int tid = threadIdx.x;
    const int wid = tid >> 6, lane = tid & 63;
    const size_t rowbase = ((size_t)(b * T_LEN + t0) * NH + h) * DH;

    // prefetch Q / Sc (bf16x8)
    const int srow = tid >> 3;
    const int scol = (tid & 7) * 8;
    bf16x8 q8[2], s8[2];
#pragma unroll
    for (int r = 0; r < 2; r++) {
        const size_t g = rowbase + (size_t)(srow + 32 * r) * INNER + scol;
        q8[r] = *(const bf16x8*)(Q + g);
        s8[r] = *(const bf16x8*)(ScB + g);
    }

    if (tid < 64)
        sexp[tid] = ExpT[(size_t)h * NROWS + b * T_LEN + t0 + tid];

#pragma unroll
    for (int r = 0; r < 2; r++) {
        *(bf16x8*)&Qb[swz(srow + 32 * r, scol)]  = q8[r];
        *(bf16x8*)&Scb[swz(srow + 32 * r, scol)] = s8[r];
    }
    __syncthreads();

    const int quad = lane >> 4;
    const int frow = lane & 15;
    const int tw = wid * 16;

    f32x4 accU[4];
#pragma unroll
    for (int i = 0; i < 4; i++) accU[i] = (f32x4)0.f;
#pragma unroll
    for (int ks = 0; ks < 2; ks++) {
        const int ko = quad * 8 + 32 * ks;
        const bf16x8 aq = *(const bf16x8*)&Qb[swz(tw + frow, ko)];
#pragma unroll
        for (int it = 0; it < 4; it++) {
            const bf16x8 bs = *(const bf16x8*)&Scb[swz(it * 16 + frow, ko)];
            accU[it] = __builtin_amdgcn_mfma_f32_16x16x32_bf16(aq, bs, accU[it], 0, 0, 0);
        }
    }

#pragma unroll
    for (int it = 0; it < 4; it++) {
#pragma unroll
        for (int r = 0; r < 4; r++) {
            const int t = tw + quad * 4 + r;
            const size_t g = rowbase + (size_t)t * INNER + it * 16 + frow;
            Yb[g] = (__bf16)(sexp[t] * accU[it][r] + (float)Yb[g]);
        }
    }
}

// ---------------------------------------------------------------------------
extern "C" void kernel_launch(void* const* d_in, const int* in_sizes, int n_in,
                              void* d_out, int out_size, void* d_ws, size_t ws_size,
                              hipStream_t stream) {
    const float* x     = (const float*)d_in[0];
    const float* state = (const float*)d_in[1];
    const float* Wq    = (const float*)d_in[2];
    const float* Wk    = (const float*)d_in[3];
    const float* Wv    = (const float*)d_in[4];
    const float* Wa    = (const float*)d_in[5];
    const float* ba    = (const float*)d_in[6];
    const float* Wb    = (const float*)d_in[7];
    const float* bb    = (const float*)d_in[8];
    const float* Wo    = (const float*)d_in[9];

    __bf16* Qb    = (__bf16*)d_ws;               // NQ bf16 (raw q, preserved)
    __bf16* Kbf   = Qb + (size_t)NQ;             // NQ bf16 (raw k)
    __bf16* Vbf   = Kbf + (size_t)NQ;            // NQ bf16 (v -> Y_intra -> Y)
    float*  DS    = (float*)(Vbf + (size_t)NQ);  // NQ fp32 (dS)
    float*  AlphaT= DS + (size_t)NQ;             // [NH][NROWS]
    float*  BetaT = AlphaT + (size_t)NROWS * NH;
    float*  ExpT  = BetaT + (size_t)NROWS * NH;  // [NH][NROWS] exp(la_t)
    float*  Dec   = ExpT + (size_t)NROWS * NH;   // per-chunk decay
    __bf16* xb    = (__bf16*)(Dec + (size_t)B_SZ * NH * NCH);
    __bf16* ScB   = xb;                          // reuse: xb dead after qkv gemm
    __bf16* WqT   = xb + (size_t)NQ;             // [WqT|WkT|WvT] contiguous
    __bf16* WkT   = WqT + (size_t)DM * INNER;
    __bf16* WvT   = WkT + (size_t)DM * INNER;
    __bf16* WoT   = WvT + (size_t)DM * INNER;

    float* out  = (float*)d_out;                // (B,T,DM)
    float* Sout = out + (size_t)NQ;             // (B,H,D,D)

    // 0) weights cast+transpose
    wt_cast_transpose<<<dim3(16, 16, 4), 256, 0, stream>>>(Wq, Wk, Wv, Wo,
                                                           WqT, WkT, WvT, WoT);
    // 1) fused gates (MFMA) + x->bf16 cast
    gates_fused<<<NROWS / 64, 256, 0, stream>>>(x, Wa, ba, Wb, bb,
                                                AlphaT, BetaT, xb);
    // 2) Q/K/V projections fused into ONE pipelined GEMM (M=8192, N=3072):
    //    768 blocks, 2 blocks/CU resident (cross-block MFMA/stage overlap).
    qkv_gemm_8ph<<<768, 256, 0, stream>>>(xb, WqT, Qb);
    // 3) intra-chunk MFMA (+fused knorm): Y_intra -> Vbf, dS -> DS
    chunk_ds<<<B_SZ * NH * NCH, 256, 0, stream>>>(Qb, Kbf, Vbf, AlphaT, BetaT,
                                                  Dec, DS, ExpT);
    // 4) serial inter-chunk state recurrence; Sc -> ScB (bf16)
    chunk_state<<<B_SZ * NH, 256, 0, stream>>>(DS, Dec, state, Sout, ScB);
    // 5) parallel Y_inter MFMA, in-place finalize of Vbf
    chunk_y<<<B_SZ * NH * NCH, 256, 0, stream>>>(Qb, ScB, Vbf, ExpT);
    // 6) output projection (pipelined, 256 blocks all co-resident)
    out_gemm_8ph<<<256, 256, 0, stream>>>(Vbf, WoT, out);
}

// Round 4
// 262.839 us; speedup vs baseline: 1.1115x; 1.0601x over previous
//
#include <hip/hip_runtime.h>
#include <hip/hip_bf16.h>
#include <math.h>

// Problem constants
#define B_SZ   4
#define T_LEN  2048
#define DM     1024
#define NH     16
#define DH     64
#define INNER  1024          // NH*DH
#define NROWS  (B_SZ*T_LEN)  // 8192
#define NQ     (NROWS*INNER) // elements per Q/K/V/Y buffer
#define CH     64            // chunk length
#define NCH    (T_LEN/CH)    // 32 chunks

typedef __bf16 bf16x8 __attribute__((ext_vector_type(8)));
typedef __bf16 bf16x4 __attribute__((ext_vector_type(4)));
typedef float  f32x4  __attribute__((ext_vector_type(4)));
typedef __attribute__((address_space(3))) void*       lds_vp;
typedef const __attribute__((address_space(1))) void* gbl_vp;

// Swizzled index into a 64x64 bf16 LDS tile: 8-elem blocks rotated by row>>2.
__device__ __forceinline__ int swz(int row, int col) {
    return (row << 6) + ((((col >> 3) + (row >> 2)) & 7) << 3) + (col & 7);
}

// ---------------------------------------------------------------------------
// Weight transpose + cast: W (K x N fp32, row-major) -> WT (N x K bf16).
// ---------------------------------------------------------------------------
__global__ __launch_bounds__(256) void wt_cast_transpose(const float* __restrict__ Wq,
                                                         const float* __restrict__ Wk,
                                                         const float* __restrict__ Wv,
                                                         const float* __restrict__ Wo,
                                                         __bf16* __restrict__ WqT,
                                                         __bf16* __restrict__ WkT,
                                                         __bf16* __restrict__ WvT,
                                                         __bf16* __restrict__ WoT) {
    __shared__ float tile[64][65];
    const float* W;
    __bf16* WT;
    if      (blockIdx.z == 0) { W = Wq; WT = WqT; }
    else if (blockIdx.z == 1) { W = Wk; WT = WkT; }
    else if (blockIdx.z == 2) { W = Wv; WT = WvT; }
    else                      { W = Wo; WT = WoT; }

    const int k0 = blockIdx.y * 64, n0 = blockIdx.x * 64;
    const int tr  = threadIdx.x >> 4;        // 0..15
    const int tc4 = (threadIdx.x & 15) * 4;  // 0..60

#pragma unroll
    for (int r = 0; r < 4; r++) {
        const int k = tr + 16 * r;
        const float4 v = *(const float4*)(W + (size_t)(k0 + k) * DM + n0 + tc4);
        tile[k][tc4 + 0] = v.x;
        tile[k][tc4 + 1] = v.y;
        tile[k][tc4 + 2] = v.z;
        tile[k][tc4 + 3] = v.w;
    }
    __syncthreads();
#pragma unroll
    for (int r = 0; r < 4; r++) {
        const int n = tr + 16 * r;
        bf16x4 o;
#pragma unroll
        for (int j = 0; j < 4; j++) o[j] = (__bf16)tile[tc4 + j][n];
        *(bf16x4*)(WT + (size_t)(n0 + n) * DM + k0 + tc4) = o;
    }
}

// ---------------------------------------------------------------------------
// 3-stage pipelined bf16 MFMA GEMM, fragment-reuse geometry (unchanged r3).
// ---------------------------------------------------------------------------
#define STAGE_STRIDE 24576          // A 16384 + B 8192 bytes
#define B_BASE 16384

template <typename CT>
__device__ __forceinline__ void gemm_pipe_body(const __bf16* __restrict__ A,
                                               const __bf16* __restrict__ BT,
                                               CT* __restrict__ C,
                                               int m0, int n0bt, int n0c) {
    __shared__ __align__(16) char lds[3 * STAGE_STRIDE];

    const int tid  = threadIdx.x;
    const int wid  = tid >> 6;       // 0..3
    const int lane = tid & 63;
    const int wm = wid >> 1;         // 0..1 : 128-row stripe
    const int wn = wid & 1;          // 0..1 : 64-col stripe
    const int frow = lane & 15, quad = lane >> 4;

    // swizzled ds_read byte offsets within one stage (loop-invariant)
    int offA[8], offB[4];
#pragma unroll
    for (int i = 0; i < 8; ++i) {
        const int ra = wm * 128 + i * 16 + frow;
        offA[i] = ra * 64 + ((quad ^ ((ra >> 1) & 3)) << 4);
    }
#pragma unroll
    for (int j = 0; j < 4; ++j) {
        const int rb = wn * 64 + j * 16 + frow;
        offB[j] = B_BASE + rb * 64 + ((quad ^ ((rb >> 1) & 3)) << 4);
    }

    // staging: per-lane pre-swizzled global source (16 rows x 64B per instr)
    const int lr = lane >> 2;                                  // row in region
    const int cs = ((lane & 3) ^ ((lane >> 3) & 3)) << 3;      // elem col (swz)
    const __bf16* gA[4];
#pragma unroll
    for (int q = 0; q < 4; ++q)
        gA[q] = A + (size_t)(m0 + wid * 64 + q * 16 + lr) * 1024 + cs;
    const __bf16* gB[2];
#pragma unroll
    for (int q = 0; q < 2; ++q)
        gB[q] = BT + (size_t)(n0bt + wid * 32 + q * 16 + lr) * 1024 + cs;

    // one staging group: 6 global_load_lds per wave (4 A + 2 B regions)
#define STG(t_, b_) do {                                                           \
        _Pragma("unroll")                                                          \
        for (int q_ = 0; q_ < 4; ++q_)                                             \
            __builtin_amdgcn_global_load_lds((gbl_vp)(gA[q_] + (size_t)(t_) * 32), \
                (lds_vp)(lds + (b_) * STAGE_STRIDE + (wid * 64 + q_ * 16) * 64),   \
                16, 0, 0);                                                         \
        _Pragma("unroll")                                                          \
        for (int q_ = 0; q_ < 2; ++q_)                                             \
            __builtin_amdgcn_global_load_lds((gbl_vp)(gB[q_] + (size_t)(t_) * 32), \
                (lds_vp)(lds + (b_) * STAGE_STRIDE + B_BASE + (wid * 32 + q_ * 16) * 64), \
                16, 0, 0);                                                         \
    } while (0)

#define VM6 asm volatile("s_waitcnt vmcnt(6)" ::: "memory")
#define VM0 asm volatile("s_waitcnt vmcnt(0)" ::: "memory")

    f32x4 acc[8][4];
#pragma unroll
    for (int i = 0; i < 8; i++)
#pragma unroll
        for (int j = 0; j < 4; j++) acc[i][j] = (f32x4)0.f;

    // prologue: stage K-tiles 0,1 (12 loads/wave in flight); wait tile 0
    STG(0, 0); STG(1, 1);
    VM6;
    asm volatile("s_barrier" ::: "memory");

    // one phase: ds_read frags || prefetch issue -> bar -> lgkm0 -> MFMA -> vm -> bar
#define PH(b_, STG_STMT, VM_STMT)                                                  \
    {                                                                              \
        const char* Sb_ = lds + (b_) * STAGE_STRIDE;                               \
        bf16x8 af_[8], bfr_[4];                                                    \
        _Pragma("unroll")                                                          \
        for (int i_ = 0; i_ < 8; ++i_) af_[i_]  = *(const bf16x8*)(Sb_ + offA[i_]);\
        _Pragma("unroll")                                                          \
        for (int j_ = 0; j_ < 4; ++j_) bfr_[j_] = *(const bf16x8*)(Sb_ + offB[j_]);\
        STG_STMT;                                                                  \
        asm volatile("s_barrier" ::: "memory");                                    \
        asm volatile("s_waitcnt lgkmcnt(0)" ::: "memory");                         \
        __builtin_amdgcn_sched_barrier(0);                                         \
        __builtin_amdgcn_s_setprio(1);                                             \
        _Pragma("unroll")                                                          \
        for (int mi_ = 0; mi_ < 8; ++mi_)                                          \
            _Pragma("unroll")                                                      \
            for (int nj_ = 0; nj_ < 4; ++nj_)                                      \
                acc[mi_][nj_] = __builtin_amdgcn_mfma_f32_16x16x32_bf16(           \
                    af_[mi_], bfr_[nj_], acc[mi_][nj_], 0, 0, 0);                  \
        __builtin_amdgcn_s_setprio(0);                                             \
        VM_STMT;                                                                   \
        asm volatile("s_barrier" ::: "memory");                                    \
    }

    // main loop: phases 0..29 (buffer residues static via unroll-by-3);
    // phase p issues the staging group for K-tile p+2.
    for (int u = 0; u < 10; ++u) {
        const int p = 3 * u;
        PH(0, STG(p + 2, 2), VM6);
        PH(1, STG(p + 3, 0), VM6);
        PH(2, STG(p + 4, 1), VM6);
    }
    // phases 30,31: drain
    PH(0, , VM0);
    PH(1, , );

#undef PH
#undef STG
#undef VM6
#undef VM0

    // epilogue: C-write (same fragment mapping as verified base kernel)
    const int cr = quad * 4, cc = frow;
#pragma unroll
    for (int mi = 0; mi < 8; ++mi) {
#pragma unroll
        for (int nj = 0; nj < 4; ++nj) {
            CT* Cp = C + (size_t)(m0 + wm * 128 + mi * 16 + cr) * 1024
                       + n0c + wn * 64 + nj * 16 + cc;
#pragma unroll
            for (int r = 0; r < 4; r++) Cp[(size_t)r * 1024] = (CT)acc[mi][nj][r];
        }
    }
}

// Fused QKV: BTall = [WqT|WkT|WvT] as [3072][1024]; QKV = [Q|K|V] contiguous.
__global__ __launch_bounds__(256, 2) void qkv_gemm_8ph(const __bf16* __restrict__ xb,
                                                       const __bf16* __restrict__ BTall,
                                                       __bf16* __restrict__ QKV) {
    const int id = blockIdx.x;
    const int wg = (id & 7) * 96 + (id >> 3);
    const int mt = wg / 24, nt = wg % 24;
    const int mat = nt >> 3;
    gemm_pipe_body<__bf16>(xb, BTall, QKV + (size_t)mat * NQ,
                           mt * 256, nt * 128, (nt & 7) * 128);
}

// Output projection: 256 blocks (32 m x 8 n), all co-resident.
__global__ __launch_bounds__(256, 2) void out_gemm_8ph(const __bf16* __restrict__ Yb,
                                                       const __bf16* __restrict__ WoT,
                                                       float* __restrict__ Cout) {
    const int id = blockIdx.x;
    const int wg = (id & 7) * 32 + (id >> 3);
    const int mt = wg >> 3, nt = wg & 7;
    gemm_pipe_body<float>(Yb, WoT, Cout, mt * 256, nt * 128, nt * 128);
}

// ---------------------------------------------------------------------------
// Fused gates + x cast (MFMA).  128 blocks x 256 thr; block = 64 rows.
// ---------------------------------------------------------------------------
#define WGS 1032   // lWg row stride (bf16): 516 dw, 4-dw bank rotation
#define LAS 40     // lA row stride (bf16): 20 dw rotation, 16B aligned
__global__ __launch_bounds__(256) void gates_fused(const float* __restrict__ x,
                                                   const float* __restrict__ Wa,
                                                   const float* __restrict__ ba,
                                                   const float* __restrict__ Wb,
                                                   const float* __restrict__ bb,
                                                   float* __restrict__ AlphaT,
                                                   float* __restrict__ BetaT,
                                                   __bf16* __restrict__ xb) {
    __shared__ __align__(16) __bf16 lWg[32 * WGS];
    __shared__ __align__(16) __bf16 lA[64 * LAS];

    const int tid = threadIdx.x;
    const int wid = tid >> 6, lane = tid & 63;
    const int quad = lane >> 4, frow = lane & 15;
    const int m0 = blockIdx.x * 64;

    // ---- stage W^T (bf16) into LDS ----
    {
        const int kbase = tid * 4;
#pragma unroll
        for (int j = 0; j < 4; j++) {
            const int k = kbase + j;
            const float4* war = (const float4*)(Wa + (size_t)k * NH);
            const float4* wbr = (const float4*)(Wb + (size_t)k * NH);
#pragma unroll
            for (int q = 0; q < 4; q++) {
                const float4 a = war[q], bq = wbr[q];
                lWg[(q * 4 + 0) * WGS + k] = (__bf16)a.x;
                lWg[(q * 4 + 1) * WGS + k] = (__bf16)a.y;
                lWg[(q * 4 + 2) * WGS + k] = (__bf16)a.z;
                lWg[(q * 4 + 3) * WGS + k] = (__bf16)a.w;
                lWg[(16 + q * 4 + 0) * WGS + k] = (__bf16)bq.x;
                lWg[(16 + q * 4 + 1) * WGS + k] = (__bf16)bq.y;
                lWg[(16 + q * 4 + 2) * WGS + k] = (__bf16)bq.z;
                lWg[(16 + q * 4 + 3) * WGS + k] = (__bf16)bq.w;
            }
        }
    }
    const float bias_a = ba[frow];
    const float bias_b = bb[frow];

    // ---- pipelined K loop ----
    const int rrow = tid >> 2;          // 0..63
    const int rk   = (tid & 3) * 8;     // 0,8,16,24
    const float* xrow = x + (size_t)(m0 + rrow) * DM + rk;
    float4 c0 = *(const float4*)(xrow + 0);
    float4 c1 = *(const float4*)(xrow + 4);

    f32x4 acc[2];
    acc[0] = (f32x4)0.f; acc[1] = (f32x4)0.f;

    for (int k0 = 0; k0 < DM; k0 += 32) {
        __syncthreads();   // prev iter's lA reads done (also covers lWg stage)
        bf16x8 xv;
        xv[0] = (__bf16)c0.x; xv[1] = (__bf16)c0.y; xv[2] = (__bf16)c0.z; xv[3] = (__bf16)c0.w;
        xv[4] = (__bf16)c1.x; xv[5] = (__bf16)c1.y; xv[6] = (__bf16)c1.z; xv[7] = (__bf16)c1.w;
        *(bf16x8*)&lA[rrow * LAS + rk] = xv;
        *(bf16x8*)(xb + (size_t)(m0 + rrow) * DM + k0 + rk) = xv;
        if (k0 + 32 < DM) {
            c0 = *(const float4*)(xrow + k0 + 32);
            c1 = *(const float4*)(xrow + k0 + 36);
        }
        __syncthreads();
        const bf16x8 af = *(const bf16x8*)&lA[(wid * 16 + frow) * LAS + quad * 8];
#pragma unroll
        for (int ct = 0; ct < 2; ct++) {
            const bf16x8 bf = *(const bf16x8*)&lWg[(ct * 16 + frow) * WGS + k0 + quad * 8];
            acc[ct] = __builtin_amdgcn_mfma_f32_16x16x32_bf16(af, bf, acc[ct], 0, 0, 0);
        }
    }

    // ---- sigmoid epilogue, transposed store ----
#pragma unroll
    for (int ct = 0; ct < 2; ct++) {
        const float bias = (ct == 0) ? bias_a : bias_b;
        float* dst = (ct == 0) ? AlphaT : BetaT;
#pragma unroll
        for (int r = 0; r < 4; r++) {
            const int row = m0 + wid * 16 + quad * 4 + r;
            const float s = acc[ct][r] + bias;
            dst[(size_t)frow * NROWS + row] = 1.f / (1.f + __expf(-s));
        }
    }
}

// ---------------------------------------------------------------------------
// Pass A (MFMA, bf16 I/O): per (b,h,c), 256 threads = 4 waves.
//   G = Q K^T ; A = mask*exp(la_t-la_s)*b_s*G ; Y_intra = A V -> V (bf16)
//   dS^T[j][i] = sum_s swd_s kn[s][j] v[s][i] -> DS (fp32, TRANSPOSED for
//   the fused scan kernel state_y).  exp(la_t) -> ExpT; decay -> Dec.
// ---------------------------------------------------------------------------
__global__ __launch_bounds__(256) void chunk_ds(const __bf16* __restrict__ Q,
                                                const __bf16* __restrict__ K,
                                                __bf16* __restrict__ V,
                                                const float* __restrict__ AlphaT,
                                                const float* __restrict__ BetaT,
                                                float* __restrict__ Dec,
                                                float* __restrict__ DS,
                                                float* __restrict__ ExpT) {
    __shared__ __align__(16) __bf16 Qb[64 * 64];
    __shared__ __align__(16) __bf16 Kb[64 * 64];
    __shared__ __align__(16) __bf16 KTs[64 * 64];  // [j][s] = swd_s * kn[s][j]
    __shared__ __align__(16) __bf16 VTb[64 * 64];  // [i][s] = V[s][i]
    __shared__ __align__(16) __bf16 Ab[64 * 64];   // [t][s]
    __shared__ float sla[64], sb[64], swd[64];

    const int blk = blockIdx.x;
    const int c = blk & 31, h = (blk >> 5) & 15, b = blk >> 9;
    const int t0 = c * CH;
    const int tid = threadIdx.x;
    const int wid = tid >> 6, lane = tid & 63;
    const size_t rowbase = ((size_t)(b * T_LEN + t0) * NH + h) * DH;

    // prefetch (16B bf16x8 per matrix per round)
    const int srow = tid >> 3;          // 0..31
    const int scol = (tid & 7) * 8;     // 0..56
    bf16x8 q8[2], k8[2], v8[2];
#pragma unroll
    for (int r = 0; r < 2; r++) {
        const size_t g = rowbase + (size_t)(srow + 32 * r) * INNER + scol;
        q8[r] = *(const bf16x8*)(Q + g);
        k8[r] = *(const bf16x8*)(K + g);
        v8[r] = *(const bf16x8*)(V + g);
    }

    // gates: prefix-sum of log(alpha) over the chunk (wave 0, coalesced)
    if (tid < 64) {
        const int t = tid;
        const size_t gaT = (size_t)h * NROWS + b * T_LEN + t0 + t;
        const float a  = AlphaT[gaT];
        const float bt = BetaT[gaT];
        float xx = logf(a);
#pragma unroll
        for (int off = 1; off < 64; off <<= 1) {
            const float y = __shfl_up(xx, off, 64);
            if (t >= off) xx += y;
        }
        const float la63 = __shfl(xx, 63, 64);
        sla[t] = xx;
        sb[t]  = bt;
        swd[t] = bt * __expf(la63 - xx);
        ExpT[gaT] = __expf(xx);
        if (t == 63) Dec[(size_t)(b * NH + h) * NCH + c] = __expf(la63);
    }
    __syncthreads();

    // stage to LDS: normalize k rows (8 lanes per row -> 3 shfl_xor)
#pragma unroll
    for (int r = 0; r < 2; r++) {
        const int row = srow + 32 * r;
        float kf[8];
        float ss = 0.f;
#pragma unroll
        for (int j = 0; j < 8; j++) { kf[j] = (float)k8[r][j]; ss += kf[j] * kf[j]; }
        ss += __shfl_xor(ss, 1, 64);
        ss += __shfl_xor(ss, 2, 64);
        ss += __shfl_xor(ss, 4, 64);
        const float scale = 1.f / fmaxf(sqrtf(ss), 1e-12f);
        const float w = swd[row];
        bf16x8 kn8;
#pragma unroll
        for (int j = 0; j < 8; j++) {
            const float kn = kf[j] * scale;
            kn8[j] = (__bf16)kn;
            KTs[swz(scol + j, row)] = (__bf16)(w * kn);
            VTb[swz(scol + j, row)] = v8[r][j];
        }
        *(bf16x8*)&Qb[swz(row, scol)] = q8[r];
        *(bf16x8*)&Kb[swz(row, scol)] = kn8;
    }
    __syncthreads();

    const int quad = lane >> 4;
    const int frow = lane & 15;
    const int tw = wid * 16;   // this wave's 16-row output stripe

    // ---- G = Q K^T ----
    f32x4 accG[4];
#pragma unroll
    for (int i = 0; i < 4; i++) accG[i] = (f32x4)0.f;
#pragma unroll
    for (int ks = 0; ks < 2; ks++) {
        const int ko = quad * 8 + 32 * ks;
        const bf16x8 aq = *(const bf16x8*)&Qb[swz(tw + frow, ko)];
#pragma unroll
        for (int st = 0; st < 4; st++) {
            const bf16x8 bk = *(const bf16x8*)&Kb[swz(st * 16 + frow, ko)];
            accG[st] = __builtin_amdgcn_mfma_f32_16x16x32_bf16(aq, bk, accG[st], 0, 0, 0);
        }
    }
    // ---- mask -> Ab (C layout: row=quad*4+r, col=frow) ----
#pragma unroll
    for (int st = 0; st < 4; st++) {
#pragma unroll
        for (int r = 0; r < 4; r++) {
            const int t = tw + quad * 4 + r;
            const int s = st * 16 + frow;
            const float av = (s <= t) ? __expf(sla[t] - sla[s]) * sb[s] * accG[st][r] : 0.f;
            Ab[swz(t, s)] = (__bf16)av;
        }
    }
    __syncthreads();

    // ---- Y_intra = A V  and  dS^T = KTs * VT^T (A/B swapped -> [j][i]) ----
    f32x4 accY[4], accD[4];
#pragma unroll
    for (int i = 0; i < 4; i++) { accY[i] = (f32x4)0.f; accD[i] = (f32x4)0.f; }
#pragma unroll
    for (int ks = 0; ks < 2; ks++) {
        const int ko = quad * 8 + 32 * ks;
        const bf16x8 aA = *(const bf16x8*)&Ab[swz(tw + frow, ko)];
        const bf16x8 aK = *(const bf16x8*)&KTs[swz(tw + frow, ko)];
#pragma unroll
        for (int jt = 0; jt < 4; jt++) {
            const bf16x8 bv = *(const bf16x8*)&VTb[swz(jt * 16 + frow, ko)];
            accY[jt] = __builtin_amdgcn_mfma_f32_16x16x32_bf16(aA, bv, accY[jt], 0, 0, 0);
            accD[jt] = __builtin_amdgcn_mfma_f32_16x16x32_bf16(aK, bv, accD[jt], 0, 0, 0);
        }
    }
    // write Y_intra (bf16) over V, dS^T (fp32) to DS (row slot = j, col = i)
#pragma unroll
    for (int jt = 0; jt < 4; jt++) {
#pragma unroll
        for (int r = 0; r < 4; r++) {
            const int row = tw + quad * 4 + r;
            const size_t g = rowbase + (size_t)row * INNER + jt * 16 + frow;
            V[g]  = (__bf16)accY[jt][r];
            DS[g] = accD[jt][r];
        }
    }
}

// ---------------------------------------------------------------------------
// Fused inter-chunk scan + Y_inter (replaces chunk_state + chunk_y).
//   256 blocks = (b, h, iq); 4 waves x 16 t-rows; state slice S[j=0..63]
//   [i = iq*16 + (lane&15)] lives in registers across the 32-chunk scan.
//   Per chunk: acc = MFMA(Q_frag, bf16(S_pre)) (2 x 16x16x32, K=j);
//   Yb[t][h*64+i] += ExpT[t]*acc ; S = dec*S + dS^T (elementwise, regs).
//   Final S -> state_out (fp32, [i][j] row-major => float4 on j).
// ---------------------------------------------------------------------------
__global__ __launch_bounds__(256) void state_y(const __bf16* __restrict__ Q,
                                               const float* __restrict__ DS,
                                               const float* __restrict__ Dec,
                                               const float* __restrict__ ExpT,
                                               const float* __restrict__ state_in,
                                               float* __restrict__ state_out,
                                               __bf16* __restrict__ Yb) {
    const int blk = blockIdx.x;
    const int b = blk >> 6, h = (blk >> 2) & 15, iq = blk & 3;
    const int tid = threadIdx.x;
    const int wid = tid >> 6, lane = tid & 63;
    const int frow = lane & 15, quad = lane >> 4;
    const int tw = wid * 16;
    const int i = iq * 16 + frow;          // this lane's state column

    // init state slice: S[ks][e] = state[b,h,i, j=32ks+quad*8+e]
    float S[2][8];
    {
        const float* st = state_in + ((size_t)((b * NH + h) * DH) + i) * DH;
#pragma unroll
        for (int ks = 0; ks < 2; ks++) {
            const int j0 = 32 * ks + quad * 8;
            const float4 a = *(const float4*)(st + j0);
            const float4 d = *(const float4*)(st + j0 + 4);
            S[ks][0] = a.x; S[ks][1] = a.y; S[ks][2] = a.z; S[ks][3] = a.w;
            S[ks][4] = d.x; S[ks][5] = d.y; S[ks][6] = d.z; S[ks][7] = d.w;
        }
    }

    const size_t bh = (size_t)(b * NH + h);
#pragma unroll 2
    for (int c = 0; c < NCH; c++) {
        const int t0 = c * CH;
        const size_t rowbase = ((size_t)(b * T_LEN + t0) * NH + h) * DH;
        const float decay = Dec[bh * NCH + c];

        // Q A-fragments first (MFMA's only memory dependency)
        const bf16x8 aq0 = *(const bf16x8*)(Q + rowbase + (size_t)(tw + frow) * INNER + quad * 8);
        const bf16x8 aq1 = *(const bf16x8*)(Q + rowbase + (size_t)(tw + frow) * INNER + 32 + quad * 8);

        // dS^T loads (scan-independent; overlap MFMA)
        float ds[2][8];
#pragma unroll
        for (int ks = 0; ks < 2; ks++) {
            const int j0 = 32 * ks + quad * 8;
#pragma unroll
            for (int e = 0; e < 8; e++)
                ds[ks][e] = DS[rowbase + (size_t)(j0 + e) * INNER + i];
        }

        // B-fragments from PRE-update state
        bf16x8 bs0, bs1;
#pragma unroll
        for (int e = 0; e < 8; e++) { bs0[e] = (__bf16)S[0][e]; bs1[e] = (__bf16)S[1][e]; }

        f32x4 acc = (f32x4)0.f;
        acc = __builtin_amdgcn_mfma_f32_16x16x32_bf16(aq0, bs0, acc, 0, 0, 0);
        acc = __builtin_amdgcn_mfma_f32_16x16x32_bf16(aq1, bs1, acc, 0, 0, 0);

        // state scan update (elementwise)
#pragma unroll
        for (int ks = 0; ks < 2; ks++)
#pragma unroll
            for (int e = 0; e < 8; e++)
                S[ks][e] = decay * S[ks][e] + ds[ks][e];

        // Yb RMW: C layout row=quad*4+r (t-sub), col=frow (i)
#pragma unroll
        for (int r = 0; r < 4; r++) {
            const int t = tw + quad * 4 + r;
            const float ee = ExpT[(size_t)h * NROWS + b * T_LEN + t0 + t];
            __bf16* yp = Yb + rowbase + (size_t)t * INNER + i;
            *yp = (__bf16)(ee * acc[r] + (float)*yp);
        }
    }

    // final state (fp32, [i][j]) -- j contiguous per lane -> float4
    float* so = state_out + ((size_t)((b * NH + h) * DH) + i) * DH;
#pragma unroll
    for (int ks = 0; ks < 2; ks++) {
        const int j0 = 32 * ks + quad * 8;
        const float4 v0 = {S[ks][0], S[ks][1], S[ks][2], S[ks][3]};
        const float4 v1 = {S[ks][4], S[ks][5], S[ks][6], S[ks][7]};
        *(float4*)(so + j0)     = v0;
        *(float4*)(so + j0 + 4) = v1;
    }
}

// ---------------------------------------------------------------------------
extern "C" void kernel_launch(void* const* d_in, const int* in_sizes, int n_in,
                              void* d_out, int out_size, void* d_ws, size_t ws_size,
                              hipStream_t stream) {
    const float* x     = (const float*)d_in[0];
    const float* state = (const float*)d_in[1];
    const float* Wq    = (const float*)d_in[2];
    const float* Wk    = (const float*)d_in[3];
    const float* Wv    = (const float*)d_in[4];
    const float* Wa    = (const float*)d_in[5];
    const float* ba    = (const float*)d_in[6];
    const float* Wb    = (const float*)d_in[7];
    const float* bb    = (const float*)d_in[8];
    const float* Wo    = (const float*)d_in[9];

    __bf16* Qb    = (__bf16*)d_ws;               // NQ bf16 (raw q, preserved)
    __bf16* Kbf   = Qb + (size_t)NQ;             // NQ bf16 (raw k)
    __bf16* Vbf   = Kbf + (size_t)NQ;            // NQ bf16 (v -> Y_intra -> Y)
    float*  DS    = (float*)(Vbf + (size_t)NQ);  // NQ fp32 (dS^T)
    float*  AlphaT= DS + (size_t)NQ;             // [NH][NROWS]
    float*  BetaT = AlphaT + (size_t)NROWS * NH;
    float*  ExpT  = BetaT + (size_t)NROWS * NH;  // [NH][NROWS] exp(la_t)
    float*  Dec   = ExpT + (size_t)NROWS * NH;   // per-chunk decay
    __bf16* xb    = (__bf16*)(Dec + (size_t)B_SZ * NH * NCH);
    __bf16* WqT   = xb + (size_t)NQ;             // [WqT|WkT|WvT] contiguous
    __bf16* WkT   = WqT + (size_t)DM * INNER;
    __bf16* WvT   = WkT + (size_t)DM * INNER;
    __bf16* WoT   = WvT + (size_t)DM * INNER;

    float* out  = (float*)d_out;                // (B,T,DM)
    float* Sout = out + (size_t)NQ;             // (B,H,D,D)

    // 0) weights cast+transpose
    wt_cast_transpose<<<dim3(16, 16, 4), 256, 0, stream>>>(Wq, Wk, Wv, Wo,
                                                           WqT, WkT, WvT, WoT);
    // 1) fused gates (MFMA) + x->bf16 cast
    gates_fused<<<NROWS / 64, 256, 0, stream>>>(x, Wa, ba, Wb, bb,
                                                AlphaT, BetaT, xb);
    // 2) Q/K/V projections fused into ONE pipelined GEMM (M=8192, N=3072)
    qkv_gemm_8ph<<<768, 256, 0, stream>>>(xb, WqT, Qb);
    // 3) intra-chunk MFMA (+fused knorm): Y_intra -> Vbf, dS^T -> DS
    chunk_ds<<<B_SZ * NH * NCH, 256, 0, stream>>>(Qb, Kbf, Vbf, AlphaT, BetaT,
                                                  Dec, DS, ExpT);
    // 4) fused inter-chunk scan + Y_inter finalize (in-register state)
    state_y<<<B_SZ * NH * 4, 256, 0, stream>>>(Qb, DS, Dec, ExpT, state,
                                               Sout, Vbf);
    // 5) output projection (pipelined, 256 blocks all co-resident)
    out_gemm_8ph<<<256, 256, 0, stream>>>(Vbf, WoT, out);
}